// Round 2
// baseline (11202.613 us; speedup 1.0000x reference)
//
#include <hip/hip_runtime.h>
#include <math.h>

#define NN 50000
#define EE 800000
#define TT 50

__device__ __forceinline__ float sigm(float x)   { return 1.f / (1.f + __expf(-x)); }
__device__ __forceinline__ float tanh_f(float x) { float e = __expf(2.f * x); return 1.f - 2.f / (e + 1.f); }

// ---------------- CSR build (counting sort by row) ----------------

__global__ __launch_bounds__(256) void hist_kernel(const int* __restrict__ idx, int* __restrict__ cnt) {
    int e = blockIdx.x * blockDim.x + threadIdx.x;
    if (e < EE) atomicAdd(&cnt[idx[2 * e]], 1);
}

__global__ __launch_bounds__(1024) void scan_kernel(const int* __restrict__ cnt, int* __restrict__ rp) {
    __shared__ int part[1024];
    const int PER = (NN + 1023) / 1024;  // 49
    int t = threadIdx.x;
    int base = t * PER;
    int s = 0;
    for (int i = 0; i < PER; ++i) {
        int idx = base + i;
        if (idx < NN) s += cnt[idx];
    }
    part[t] = s;
    __syncthreads();
    int v = s;
    for (int off = 1; off < 1024; off <<= 1) {
        int add = (t >= off) ? part[t - off] : 0;
        __syncthreads();
        v += add;
        part[t] = v;
        __syncthreads();
    }
    int run = v - s;  // exclusive prefix of this thread's chunk
    if (t == 0) rp[0] = 0;
    for (int i = 0; i < PER; ++i) {
        int idx = base + i;
        if (idx < NN) { run += cnt[idx]; rp[idx + 1] = run; }
    }
}

__global__ __launch_bounds__(256) void scatter_kernel(const int* __restrict__ idx, const float* __restrict__ val,
                                                      const int* __restrict__ rp, int* __restrict__ cnt,
                                                      int* __restrict__ cs, float* __restrict__ vs) {
    int e = blockIdx.x * blockDim.x + threadIdx.x;
    if (e >= EE) return;
    int r = idx[2 * e];
    int p = rp[r] + atomicAdd(&cnt[r], 1);
    cs[p] = idx[2 * e + 1];
    vs[p] = val[e];
}

// ---------------- SpMM kernels (CSR, one wave per row) ----------------

// 65-col pass: [x | h1], writes Sh (N x 64) and Sx (N)
__global__ __launch_bounds__(256) void spmm_p1(const int* __restrict__ rp, const int* __restrict__ cs,
                                               const float* __restrict__ vs, const float* __restrict__ h,
                                               const float* __restrict__ x,
                                               float* __restrict__ Sh, float* __restrict__ Sx) {
    int w = (blockIdx.x * blockDim.x + threadIdx.x) >> 6;
    int lane = threadIdx.x & 63;
    if (w >= NN) return;
    int e = rp[w], e1 = rp[w + 1];
    float a0 = 0.f, a1 = 0.f, ax0 = 0.f, ax1 = 0.f;
    for (; e + 1 < e1; e += 2) {
        int c0 = cs[e], c1 = cs[e + 1];
        float v0 = vs[e], v1 = vs[e + 1];
        a0  = fmaf(v0, h[c0 * 64 + lane], a0);
        ax0 = fmaf(v0, x[c0], ax0);
        a1  = fmaf(v1, h[c1 * 64 + lane], a1);
        ax1 = fmaf(v1, x[c1], ax1);
    }
    if (e < e1) {
        int c = cs[e]; float v = vs[e];
        a0  = fmaf(v, h[c * 64 + lane], a0);
        ax0 = fmaf(v, x[c], ax0);
    }
    Sh[w * 64 + lane] = a0 + a1;
    if (lane == 0) Sx[w] = ax0 + ax1;
}

// 64-col pass
__global__ __launch_bounds__(256) void spmm64(const int* __restrict__ rp, const int* __restrict__ cs,
                                              const float* __restrict__ vs, const float* __restrict__ Xin,
                                              float* __restrict__ Sout) {
    int w = (blockIdx.x * blockDim.x + threadIdx.x) >> 6;
    int lane = threadIdx.x & 63;
    if (w >= NN) return;
    int e = rp[w], e1 = rp[w + 1];
    float a0 = 0.f, a1 = 0.f;
    for (; e + 1 < e1; e += 2) {
        int c0 = cs[e], c1 = cs[e + 1];
        a0 = fmaf(vs[e],     Xin[c0 * 64 + lane], a0);
        a1 = fmaf(vs[e + 1], Xin[c1 * 64 + lane], a1);
    }
    if (e < e1) a0 = fmaf(vs[e], Xin[cs[e] * 64 + lane], a0);
    Sout[w * 64 + lane] = a0 + a1;
}

// 8-col pass: 8 lanes per row
__global__ __launch_bounds__(256) void spmm_p8(const int* __restrict__ rp, const int* __restrict__ cs,
                                               const float* __restrict__ vs, const float* __restrict__ z,
                                               float* __restrict__ S3) {
    int gid = blockIdx.x * blockDim.x + threadIdx.x;
    int row = gid >> 3;
    int j = gid & 7;
    if (row >= NN) return;
    int e = rp[row], e1 = rp[row + 1];
    float a0 = 0.f, a1 = 0.f;
    for (; e + 1 < e1; e += 2) {
        a0 = fmaf(vs[e],     z[cs[e] * 8 + j],     a0);
        a1 = fmaf(vs[e + 1], z[cs[e + 1] * 8 + j], a1);
    }
    if (e < e1) a0 = fmaf(vs[e], z[cs[e] * 8 + j], a0);
    S3[row * 8 + j] = a0 + a1;
}

// 2-col pass: 2 lanes per row
__global__ __launch_bounds__(256) void spmm_p2k(const int* __restrict__ rp, const int* __restrict__ cs,
                                                const float* __restrict__ vs, const float* __restrict__ z,
                                                float* __restrict__ S4) {
    int gid = blockIdx.x * blockDim.x + threadIdx.x;
    int row = gid >> 1;
    int j = gid & 1;
    if (row >= NN) return;
    int e = rp[row], e1 = rp[row + 1];
    float a0 = 0.f, a1 = 0.f;
    for (; e + 1 < e1; e += 2) {
        a0 = fmaf(vs[e],     z[cs[e] * 2 + j],     a0);
        a1 = fmaf(vs[e + 1], z[cs[e + 1] * 2 + j], a1);
    }
    if (e < e1) a0 = fmaf(vs[e], z[cs[e] * 2 + j], a0);
    S4[row * 2 + j] = a0 + a1;
}

// ---------------- Layer-1 dense kernels ----------------

// ru = sigmoid([Sx|Sh] @ W1_g + b); store rh = r*h1 and u
#define G1_CHUNK 32
__global__ __launch_bounds__(128) void gate1(const float* __restrict__ Sh, const float* __restrict__ Sx,
                                             const float* __restrict__ Wg, const float* __restrict__ bg,
                                             const float* __restrict__ h1,
                                             float* __restrict__ rh, float* __restrict__ u1) {
    __shared__ float s[G1_CHUNK][68];
    int j = threadIdx.x;  // 0..127 output column
    float w[65];
#pragma unroll
    for (int k = 0; k < 65; ++k) w[k] = Wg[k * 128 + j];
    float bj = bg[j];
    int nChunks = (NN + G1_CHUNK - 1) / G1_CHUNK;
    for (int ch = blockIdx.x; ch < nChunks; ch += gridDim.x) {
        int n0 = ch * G1_CHUNK;
        __syncthreads();
        for (int i = j; i < G1_CHUNK * 64; i += 128) {
            int n = i >> 6, k = i & 63;
            if (n0 + n < NN) s[n][k + 1] = Sh[(n0 + n) * 64 + k];
        }
        if (j < G1_CHUNK && n0 + j < NN) s[j][0] = Sx[n0 + j];
        __syncthreads();
        int nmax = min(G1_CHUNK, NN - n0);
        for (int n = 0; n < nmax; ++n) {
            float acc = bj;
#pragma unroll
            for (int k = 0; k < 65; ++k) acc = fmaf(s[n][k], w[k], acc);
            float g = sigm(acc);
            int node = n0 + n;
            if (j < 64) rh[node * 64 + j] = g * h1[node * 64 + j];
            else        u1[node * 64 + (j - 64)] = g;
        }
    }
}

// c = tanh([Sx|S2] @ W1_c + b); h1 = u*h1+(1-u)*c; z8[0..5] = h1new @ Wcat
__global__ __launch_bounds__(256) void cand_update(const float* __restrict__ S2, const float* __restrict__ Sx,
                                                   const float* __restrict__ Wc, const float* __restrict__ bc,
                                                   const float* __restrict__ u1, float* __restrict__ h1,
                                                   const float* __restrict__ Wbg, const float* __restrict__ Wbc,
                                                   const float* __restrict__ Wug, const float* __restrict__ Wuc,
                                                   float* __restrict__ z8) {
    int j = threadIdx.x & 63;
    int g = threadIdx.x >> 6;
    float w[65];
#pragma unroll
    for (int k = 0; k < 65; ++k) w[k] = Wc[k * 64 + j];
    float bj = bc[j];
    float wz0 = Wbg[j * 2], wz1 = Wbg[j * 2 + 1], wz2 = Wbc[j];
    float wz3 = Wug[j * 2], wz4 = Wug[j * 2 + 1], wz5 = Wuc[j];
    for (int n = blockIdx.x * 4 + g; n < NN; n += gridDim.x * 4) {
        float acc = fmaf(Sx[n], w[0], bj);
        const float4* s2 = (const float4*)(S2 + n * 64);
#pragma unroll
        for (int q = 0; q < 16; ++q) {
            float4 sv = s2[q];
            acc = fmaf(sv.x, w[1 + 4 * q], acc);
            acc = fmaf(sv.y, w[2 + 4 * q], acc);
            acc = fmaf(sv.z, w[3 + 4 * q], acc);
            acc = fmaf(sv.w, w[4 + 4 * q], acc);
        }
        float c = tanh_f(acc);
        float u = u1[n * 64 + j];
        float ho = h1[n * 64 + j];
        float hn = fmaf(u, ho - c, c);  // u*h + (1-u)*c
        h1[n * 64 + j] = hn;
        float p0 = hn * wz0, p1 = hn * wz1, p2 = hn * wz2;
        float p3 = hn * wz3, p4 = hn * wz4, p5 = hn * wz5;
#pragma unroll
        for (int off = 1; off < 64; off <<= 1) {
            p0 += __shfl_xor(p0, off);
            p1 += __shfl_xor(p1, off);
            p2 += __shfl_xor(p2, off);
            p3 += __shfl_xor(p3, off);
            p4 += __shfl_xor(p4, off);
            p5 += __shfl_xor(p5, off);
        }
        if (j == 0) {
            z8[n * 8 + 0] = p0; z8[n * 8 + 1] = p1; z8[n * 8 + 2] = p2;
            z8[n * 8 + 3] = p3; z8[n * 8 + 4] = p4; z8[n * 8 + 5] = p5;
        }
    }
}

// ---------------- Layer-2 (units=1, b & u merged) ----------------

// gates: r_b,u_b,r_u,u_u from S3; store z2 = [r_b*h_b, r_u*h_u], g2 = [u_b, u_u]
__global__ __launch_bounds__(256) void gate2(const float* __restrict__ S3,
                                             const float* __restrict__ hb, const float* __restrict__ hu,
                                             const float* __restrict__ Wbg, const float* __restrict__ bbg,
                                             const float* __restrict__ Wug, const float* __restrict__ bug,
                                             float* __restrict__ z2, float* __restrict__ g2) {
    int n = blockIdx.x * blockDim.x + threadIdx.x;
    if (n >= NN) return;
    float wb0 = Wbg[128], wb1 = Wbg[129];  // row 64 of (65,2)
    float wu0 = Wug[128], wu1 = Wug[129];
    float b0 = bbg[0], b1 = bbg[1], c0 = bug[0], c1 = bug[1];
    float s0 = S3[n * 8 + 0], s1 = S3[n * 8 + 1];
    float s3 = S3[n * 8 + 3], s4 = S3[n * 8 + 4];
    float s6 = S3[n * 8 + 6], s7 = S3[n * 8 + 7];
    float rb = sigm(fmaf(s6, wb0, s0) + b0);
    float ub = sigm(fmaf(s6, wb1, s1) + b1);
    float ru = sigm(fmaf(s7, wu0, s3) + c0);
    float uu = sigm(fmaf(s7, wu1, s4) + c1);
    z2[n * 2 + 0] = rb * hb[n];
    z2[n * 2 + 1] = ru * hu[n];
    g2[n * 2 + 0] = ub;
    g2[n * 2 + 1] = uu;
}

// candidates + state update + output write + z8[6,7] for next step
__global__ __launch_bounds__(256) void update2(const float* __restrict__ S3, const float* __restrict__ S4,
                                               const float* __restrict__ g2,
                                               const float* __restrict__ Wbc, const float* __restrict__ bbc,
                                               const float* __restrict__ Wuc, const float* __restrict__ buc,
                                               float* __restrict__ hb, float* __restrict__ hu,
                                               float* __restrict__ z8, float* __restrict__ out, int t) {
    int n = blockIdx.x * blockDim.x + threadIdx.x;
    if (n >= NN) return;
    float wb = Wbc[64], bb = bbc[0];
    float wu = Wuc[64], bu = buc[0];
    float cb = tanh_f(fmaf(S4[n * 2 + 0], wb, S3[n * 8 + 2]) + bb);
    float cu = tanh_f(fmaf(S4[n * 2 + 1], wu, S3[n * 8 + 5]) + bu);
    float ub = g2[n * 2 + 0], uu = g2[n * 2 + 1];
    float hbn = fmaf(ub, hb[n] - cb, cb);
    float hun = fmaf(uu, hu[n] - cu, cu);
    hb[n] = hbn; hu[n] = hun;
    z8[n * 8 + 6] = hbn;
    z8[n * 8 + 7] = hun;
    out[(size_t)t * NN + n] = hbn;
    out[(size_t)(TT + t) * NN + n] = hun;
}

// ---------------- host ----------------

extern "C" void kernel_launch(void* const* d_in, const int* in_sizes, int n_in,
                              void* d_out, int out_size, void* d_ws, size_t ws_size,
                              hipStream_t stream) {
    const float* features = (const float*)d_in[0];
    const int*   index    = (const int*)d_in[1];
    const float* value    = (const float*)d_in[2];
    const float* W1g  = (const float*)d_in[3];
    const float* b1g  = (const float*)d_in[4];
    const float* W1c  = (const float*)d_in[5];
    const float* b1c  = (const float*)d_in[6];
    const float* W2bg = (const float*)d_in[7];
    const float* b2bg = (const float*)d_in[8];
    const float* W2bc = (const float*)d_in[9];
    const float* b2bc = (const float*)d_in[10];
    const float* W2ug = (const float*)d_in[11];
    const float* b2ug = (const float*)d_in[12];
    const float* W2uc = (const float*)d_in[13];
    const float* b2uc = (const float*)d_in[14];
    float* out = (float*)d_out;

    char* ws = (char*)d_ws;
    size_t o = 0;
    auto alloc = [&](size_t bytes) { size_t cur = o; o += (bytes + 255) & ~(size_t)255; return cur; };
    size_t o_h1  = alloc((size_t)NN * 64 * 4);
    size_t o_hb  = alloc((size_t)NN * 4);
    size_t o_hu  = alloc((size_t)NN * 4);
    size_t o_z8  = alloc((size_t)NN * 8 * 4);
    size_t zeroEnd = o;
    size_t o_rp  = alloc((size_t)(NN + 1) * 4);
    size_t o_cnt = alloc((size_t)NN * 4);
    size_t o_cs  = alloc((size_t)EE * 4);
    size_t o_vs  = alloc((size_t)EE * 4);
    size_t o_S1h = alloc((size_t)NN * 64 * 4);
    size_t o_S1x = alloc((size_t)NN * 4);
    size_t o_rh  = alloc((size_t)NN * 64 * 4);
    size_t o_u1  = alloc((size_t)NN * 64 * 4);
    size_t o_S2  = alloc((size_t)NN * 64 * 4);
    size_t o_S3  = alloc((size_t)NN * 8 * 4);
    size_t o_z2  = alloc((size_t)NN * 2 * 4);
    size_t o_S4  = alloc((size_t)NN * 2 * 4);
    size_t o_g2  = alloc((size_t)NN * 2 * 4);
    (void)ws_size; (void)in_sizes; (void)n_in; (void)out_size;

    float* h1  = (float*)(ws + o_h1);
    float* hb  = (float*)(ws + o_hb);
    float* hu  = (float*)(ws + o_hu);
    float* z8  = (float*)(ws + o_z8);
    int*   rp  = (int*)(ws + o_rp);
    int*   cnt = (int*)(ws + o_cnt);
    int*   cs  = (int*)(ws + o_cs);
    float* vsr = (float*)(ws + o_vs);
    float* S1h = (float*)(ws + o_S1h);
    float* S1x = (float*)(ws + o_S1x);
    float* rh  = (float*)(ws + o_rh);
    float* u1  = (float*)(ws + o_u1);
    float* S2  = (float*)(ws + o_S2);
    float* S3  = (float*)(ws + o_S3);
    float* z2  = (float*)(ws + o_z2);
    float* S4  = (float*)(ws + o_S4);
    float* g2  = (float*)(ws + o_g2);

    // CSR build
    (void)hipMemsetAsync(ws + o_cnt, 0, (size_t)NN * 4, stream);
    hist_kernel<<<(EE + 255) / 256, 256, 0, stream>>>(index, cnt);
    scan_kernel<<<1, 1024, 0, stream>>>(cnt, rp);
    (void)hipMemsetAsync(ws + o_cnt, 0, (size_t)NN * 4, stream);
    scatter_kernel<<<(EE + 255) / 256, 256, 0, stream>>>(index, value, rp, cnt, cs, vsr);

    // zero states: h1, hb, hu, z8 (contiguous region)
    (void)hipMemsetAsync(ws + o_h1, 0, zeroEnd - o_h1, stream);

    for (int t = 0; t < TT; ++t) {
        const float* xt = features + (size_t)t * NN;
        spmm_p1<<<(NN + 3) / 4, 256, 0, stream>>>(rp, cs, vsr, h1, xt, S1h, S1x);
        gate1<<<784, 128, 0, stream>>>(S1h, S1x, W1g, b1g, h1, rh, u1);
        spmm64<<<(NN + 3) / 4, 256, 0, stream>>>(rp, cs, vsr, rh, S2);
        cand_update<<<1024, 256, 0, stream>>>(S2, S1x, W1c, b1c, u1, h1, W2bg, W2bc, W2ug, W2uc, z8);
        spmm_p8<<<(NN * 8 + 255) / 256, 256, 0, stream>>>(rp, cs, vsr, z8, S3);
        gate2<<<(NN + 255) / 256, 256, 0, stream>>>(S3, hb, hu, W2bg, b2bg, W2ug, b2ug, z2, g2);
        spmm_p2k<<<(NN * 2 + 255) / 256, 256, 0, stream>>>(rp, cs, vsr, z2, S4);
        update2<<<(NN + 255) / 256, 256, 0, stream>>>(S3, S4, g2, W2bc, b2bc, W2uc, b2uc, hb, hu, z8, out, t);
    }
}

// Round 4
// 10906.818 us; speedup vs baseline: 1.0271x; 1.0271x over previous
//
#include <hip/hip_runtime.h>
#include <math.h>

#define NN 50000
#define EE 800000
#define TT 50

__device__ __forceinline__ float sigm(float x)   { return 1.f / (1.f + __expf(-x)); }
__device__ __forceinline__ float tanh_f(float x) { float e = __expf(2.f * x); return 1.f - 2.f / (e + 1.f); }

// ---------------- CSR build (counting sort by row) ----------------

__global__ __launch_bounds__(256) void hist_kernel(const int* __restrict__ idx, int* __restrict__ cnt) {
    int e = blockIdx.x * blockDim.x + threadIdx.x;
    if (e < EE) atomicAdd(&cnt[idx[2 * e]], 1);
}

__global__ __launch_bounds__(1024) void scan_kernel(const int* __restrict__ cnt, int* __restrict__ rp) {
    __shared__ int part[1024];
    const int PER = (NN + 1023) / 1024;  // 49
    int t = threadIdx.x;
    int base = t * PER;
    int s = 0;
    for (int i = 0; i < PER; ++i) {
        int idx = base + i;
        if (idx < NN) s += cnt[idx];
    }
    part[t] = s;
    __syncthreads();
    int v = s;
    for (int off = 1; off < 1024; off <<= 1) {
        int add = (t >= off) ? part[t - off] : 0;
        __syncthreads();
        v += add;
        part[t] = v;
        __syncthreads();
    }
    int run = v - s;  // exclusive prefix of this thread's chunk
    if (t == 0) rp[0] = 0;
    for (int i = 0; i < PER; ++i) {
        int idx = base + i;
        if (idx < NN) { run += cnt[idx]; rp[idx + 1] = run; }
    }
}

// edge record: .x = col, .y = bit-cast float value
__global__ __launch_bounds__(256) void scatter_kernel(const int* __restrict__ idx, const float* __restrict__ val,
                                                      const int* __restrict__ rp, int* __restrict__ cnt,
                                                      int2* __restrict__ ev) {
    int e = blockIdx.x * blockDim.x + threadIdx.x;
    if (e >= EE) return;
    int r = idx[2 * e];
    int p = rp[r] + atomicAdd(&cnt[r], 1);
    ev[p] = make_int2(idx[2 * e + 1], __float_as_int(val[e]));
}

// ---------------- SpMM kernels (CSR) ----------------

// 65-col pass: gathers fp32 h rows + fp32 x; writes Sh (N x 64) and Sx (N)
__global__ __launch_bounds__(256) void spmm_p1(const int* __restrict__ rp, const int2* __restrict__ ev,
                                               const float* __restrict__ h, const float* __restrict__ x,
                                               float* __restrict__ Sh, float* __restrict__ Sx) {
    int w = (blockIdx.x * blockDim.x + threadIdx.x) >> 6;
    int lane = threadIdx.x & 63;
    if (w >= NN) return;
    int e = rp[w], e1 = rp[w + 1];
    float a0 = 0.f, a1 = 0.f, ax0 = 0.f, ax1 = 0.f;
    for (; e + 1 < e1; e += 2) {
        int2 p0 = ev[e], p1 = ev[e + 1];
        float v0 = __int_as_float(p0.y), v1 = __int_as_float(p1.y);
        a0  = fmaf(v0, h[p0.x * 64 + lane], a0);
        ax0 = fmaf(v0, x[p0.x], ax0);
        a1  = fmaf(v1, h[p1.x * 64 + lane], a1);
        ax1 = fmaf(v1, x[p1.x], ax1);
    }
    if (e < e1) {
        int2 p = ev[e]; float v = __int_as_float(p.y);
        a0  = fmaf(v, h[p.x * 64 + lane], a0);
        ax0 = fmaf(v, x[p.x], ax0);
    }
    Sh[w * 64 + lane] = a0 + a1;
    if (lane == 0) Sx[w] = ax0 + ax1;
}

// 64-col pass over fp32 input
__global__ __launch_bounds__(256) void spmm64(const int* __restrict__ rp, const int2* __restrict__ ev,
                                              const float* __restrict__ Xin, float* __restrict__ Sout) {
    int w = (blockIdx.x * blockDim.x + threadIdx.x) >> 6;
    int lane = threadIdx.x & 63;
    if (w >= NN) return;
    int e = rp[w], e1 = rp[w + 1];
    float a0 = 0.f, a1 = 0.f;
    for (; e + 1 < e1; e += 2) {
        int2 p0 = ev[e], p1 = ev[e + 1];
        a0 = fmaf(__int_as_float(p0.y), Xin[p0.x * 64 + lane], a0);
        a1 = fmaf(__int_as_float(p1.y), Xin[p1.x * 64 + lane], a1);
    }
    if (e < e1) {
        int2 p = ev[e];
        a0 = fmaf(__int_as_float(p.y), Xin[p.x * 64 + lane], a0);
    }
    Sout[w * 64 + lane] = a0 + a1;
}

// ---------------- Layer-1 dense kernels ----------------

// ru = sigmoid([Sx|Sh] @ W1_g + b); store rh = r*h1 (fp32) and u (fp32)
#define G1_CHUNK 32
__global__ __launch_bounds__(128) void gate1(const float* __restrict__ Sh, const float* __restrict__ Sx,
                                             const float* __restrict__ Wg, const float* __restrict__ bg,
                                             const float* __restrict__ h1,
                                             float* __restrict__ rh, float* __restrict__ u1) {
    __shared__ float4 s4[G1_CHUNK][16];
    __shared__ float sxl[G1_CHUNK];
    int j = threadIdx.x;  // 0..127 output column
    float w0 = Wg[j];     // row 0 (x part)
    float wk[64];
#pragma unroll
    for (int k = 0; k < 64; ++k) wk[k] = Wg[(1 + k) * 128 + j];
    float bj = bg[j];
    int nChunks = (NN + G1_CHUNK - 1) / G1_CHUNK;
    for (int ch = blockIdx.x; ch < nChunks; ch += gridDim.x) {
        int n0 = ch * G1_CHUNK;
        int nmax = min(G1_CHUNK, NN - n0);
        __syncthreads();
        for (int idx = j; idx < G1_CHUNK * 16; idx += 128) {
            int n = idx >> 4, q = idx & 15;
            if (n < nmax) s4[n][q] = *(const float4*)(Sh + (size_t)(n0 + n) * 64 + q * 4);
        }
        if (j < G1_CHUNK && j < nmax) sxl[j] = Sx[n0 + j];
        __syncthreads();
        for (int n = 0; n < nmax; ++n) {
            float acc = fmaf(sxl[n], w0, bj);
#pragma unroll
            for (int q = 0; q < 16; ++q) {
                float4 sv = s4[n][q];  // broadcast read
                acc = fmaf(sv.x, wk[4 * q + 0], acc);
                acc = fmaf(sv.y, wk[4 * q + 1], acc);
                acc = fmaf(sv.z, wk[4 * q + 2], acc);
                acc = fmaf(sv.w, wk[4 * q + 3], acc);
            }
            float g = sigm(acc);
            int node = n0 + n;
            if (j < 64) rh[node * 64 + j] = g * h1[node * 64 + j];
            else        u1[node * 64 + (j - 64)] = g;
        }
    }
}

// c = tanh([Sx|S2] @ W1_c + b); h1 = u*h1+(1-u)*c; z8[0..5] = h1new @ Wcat
__global__ __launch_bounds__(256) void cand_update(const float* __restrict__ S2, const float* __restrict__ Sx,
                                                   const float* __restrict__ Wc, const float* __restrict__ bc,
                                                   const float* __restrict__ u1, float* __restrict__ h1,
                                                   const float* __restrict__ Wbg, const float* __restrict__ Wbc,
                                                   const float* __restrict__ Wug, const float* __restrict__ Wuc,
                                                   float* __restrict__ z8) {
    int j = threadIdx.x & 63;
    int g = threadIdx.x >> 6;
    float w[65];
#pragma unroll
    for (int k = 0; k < 65; ++k) w[k] = Wc[k * 64 + j];
    float bj = bc[j];
    float wz0 = Wbg[j * 2], wz1 = Wbg[j * 2 + 1], wz2 = Wbc[j];
    float wz3 = Wug[j * 2], wz4 = Wug[j * 2 + 1], wz5 = Wuc[j];
    for (int n = blockIdx.x * 4 + g; n < NN; n += gridDim.x * 4) {
        float acc = fmaf(Sx[n], w[0], bj);
        const float4* s2 = (const float4*)(S2 + n * 64);
#pragma unroll
        for (int q = 0; q < 16; ++q) {
            float4 sv = s2[q];
            acc = fmaf(sv.x, w[1 + 4 * q], acc);
            acc = fmaf(sv.y, w[2 + 4 * q], acc);
            acc = fmaf(sv.z, w[3 + 4 * q], acc);
            acc = fmaf(sv.w, w[4 + 4 * q], acc);
        }
        float c = tanh_f(acc);
        float u = u1[n * 64 + j];
        float ho = h1[n * 64 + j];
        float hn = fmaf(u, ho - c, c);  // u*h + (1-u)*c
        h1[n * 64 + j] = hn;
        float p0 = hn * wz0, p1 = hn * wz1, p2 = hn * wz2;
        float p3 = hn * wz3, p4 = hn * wz4, p5 = hn * wz5;
#pragma unroll
        for (int off = 1; off < 64; off <<= 1) {
            p0 += __shfl_xor(p0, off);
            p1 += __shfl_xor(p1, off);
            p2 += __shfl_xor(p2, off);
            p3 += __shfl_xor(p3, off);
            p4 += __shfl_xor(p4, off);
            p5 += __shfl_xor(p5, off);
        }
        if (j == 0) {
            z8[n * 8 + 0] = p0; z8[n * 8 + 1] = p1; z8[n * 8 + 2] = p2;
            z8[n * 8 + 3] = p3; z8[n * 8 + 4] = p4; z8[n * 8 + 5] = p5;
        }
    }
}

// ---------------- Layer-2 fused kernels ----------------

// spmm over z8 (8 lanes/row) + gate2 epilogue. Writes z2, g2, S3c (cand x-parts).
__global__ __launch_bounds__(256) void spmm8_gate2(const int* __restrict__ rp, const int2* __restrict__ ev,
                                                   const float* __restrict__ z8,
                                                   const float* __restrict__ hb, const float* __restrict__ hu,
                                                   const float* __restrict__ Wbg, const float* __restrict__ bbg,
                                                   const float* __restrict__ Wug, const float* __restrict__ bug,
                                                   float* __restrict__ z2, float* __restrict__ g2,
                                                   float* __restrict__ S3c) {
    int gid = blockIdx.x * blockDim.x + threadIdx.x;
    int row = gid >> 3;
    int j = gid & 7;
    if (row >= NN) return;
    int e = rp[row], e1 = rp[row + 1];
    float a0 = 0.f, a1 = 0.f;
    for (; e + 1 < e1; e += 2) {
        int2 p0 = ev[e], p1 = ev[e + 1];
        a0 = fmaf(__int_as_float(p0.y), z8[p0.x * 8 + j], a0);
        a1 = fmaf(__int_as_float(p1.y), z8[p1.x * 8 + j], a1);
    }
    if (e < e1) { int2 p = ev[e]; a0 = fmaf(__int_as_float(p.y), z8[p.x * 8 + j], a0); }
    float s = a0 + a1;
    if (j == 2) S3c[row * 2 + 0] = s;
    if (j == 5) S3c[row * 2 + 1] = s;
    int lane = threadIdx.x & 63;
    int base = lane & ~7;
    float s0 = __shfl(s, base + 0);
    float s1 = __shfl(s, base + 1);
    float s3 = __shfl(s, base + 3);
    float s4 = __shfl(s, base + 4);
    float s6 = __shfl(s, base + 6);
    float s7 = __shfl(s, base + 7);
    if (j == 0) {
        float rb = sigm(fmaf(s6, Wbg[128], s0) + bbg[0]);
        float ub = sigm(fmaf(s6, Wbg[129], s1) + bbg[1]);
        float ru = sigm(fmaf(s7, Wug[128], s3) + bug[0]);
        float uu = sigm(fmaf(s7, Wug[129], s4) + bug[1]);
        z2[row * 2 + 0] = rb * hb[row];
        z2[row * 2 + 1] = ru * hu[row];
        g2[row * 2 + 0] = ub;
        g2[row * 2 + 1] = uu;
    }
}

// spmm over z2 (2 lanes/row) + update2 epilogue. Writes hb, hu, z8[6,7], out.
__global__ __launch_bounds__(256) void spmm2_update2(const int* __restrict__ rp, const int2* __restrict__ ev,
                                                     const float* __restrict__ z2,
                                                     const float* __restrict__ S3c, const float* __restrict__ g2,
                                                     const float* __restrict__ Wbc, const float* __restrict__ bbc,
                                                     const float* __restrict__ Wuc, const float* __restrict__ buc,
                                                     float* __restrict__ hb, float* __restrict__ hu,
                                                     float* __restrict__ z8, float* __restrict__ out, int t) {
    int gid = blockIdx.x * blockDim.x + threadIdx.x;
    int row = gid >> 1;
    int j = gid & 1;
    if (row >= NN) return;
    int e = rp[row], e1 = rp[row + 1];
    float a0 = 0.f, a1 = 0.f;
    for (; e + 1 < e1; e += 2) {
        int2 p0 = ev[e], p1 = ev[e + 1];
        a0 = fmaf(__int_as_float(p0.y), z2[p0.x * 2 + j], a0);
        a1 = fmaf(__int_as_float(p1.y), z2[p1.x * 2 + j], a1);
    }
    if (e < e1) { int2 p = ev[e]; a0 = fmaf(__int_as_float(p.y), z2[p.x * 2 + j], a0); }
    float s = a0 + a1;
    int lane = threadIdx.x & 63;
    int base = lane & ~1;
    float sA = __shfl(s, base + 0);
    float sB = __shfl(s, base + 1);
    if (j == 0) {
        float cb = tanh_f(fmaf(sA, Wbc[64], S3c[row * 2 + 0]) + bbc[0]);
        float cu = tanh_f(fmaf(sB, Wuc[64], S3c[row * 2 + 1]) + buc[0]);
        float ub = g2[row * 2 + 0], uu = g2[row * 2 + 1];
        float hbn = fmaf(ub, hb[row] - cb, cb);
        float hun = fmaf(uu, hu[row] - cu, cu);
        hb[row] = hbn; hu[row] = hun;
        z8[row * 8 + 6] = hbn;
        z8[row * 8 + 7] = hun;
        out[(size_t)t * NN + row] = hbn;
        out[(size_t)(TT + t) * NN + row] = hun;
    }
}

// ---------------- host ----------------

extern "C" void kernel_launch(void* const* d_in, const int* in_sizes, int n_in,
                              void* d_out, int out_size, void* d_ws, size_t ws_size,
                              hipStream_t stream) {
    const float* features = (const float*)d_in[0];
    const int*   index    = (const int*)d_in[1];
    const float* value    = (const float*)d_in[2];
    const float* W1g  = (const float*)d_in[3];
    const float* b1g  = (const float*)d_in[4];
    const float* W1c  = (const float*)d_in[5];
    const float* b1c  = (const float*)d_in[6];
    const float* W2bg = (const float*)d_in[7];
    const float* b2bg = (const float*)d_in[8];
    const float* W2bc = (const float*)d_in[9];
    const float* b2bc = (const float*)d_in[10];
    const float* W2ug = (const float*)d_in[11];
    const float* b2ug = (const float*)d_in[12];
    const float* W2uc = (const float*)d_in[13];
    const float* b2uc = (const float*)d_in[14];
    float* out = (float*)d_out;

    char* ws = (char*)d_ws;
    size_t o = 0;
    auto alloc = [&](size_t bytes) { size_t cur = o; o += (bytes + 255) & ~(size_t)255; return cur; };
    // zero-init region: h1, hb, hu, z8 (contiguous)
    size_t o_h1  = alloc((size_t)NN * 64 * 4);
    size_t o_hb  = alloc((size_t)NN * 4);
    size_t o_hu  = alloc((size_t)NN * 4);
    size_t o_z8  = alloc((size_t)NN * 8 * 4);
    size_t zeroEnd = o;
    size_t o_rp  = alloc((size_t)(NN + 1) * 4);
    size_t o_cnt = alloc((size_t)NN * 4);
    size_t o_ev  = alloc((size_t)EE * 8);
    size_t o_Sh  = alloc((size_t)NN * 64 * 4);
    size_t o_Sx  = alloc((size_t)NN * 4);
    size_t o_rh  = alloc((size_t)NN * 64 * 4);
    size_t o_u1  = alloc((size_t)NN * 64 * 4);
    size_t o_S2  = alloc((size_t)NN * 64 * 4);
    size_t o_S3c = alloc((size_t)NN * 2 * 4);
    size_t o_z2  = alloc((size_t)NN * 2 * 4);
    size_t o_g2  = alloc((size_t)NN * 2 * 4);
    (void)ws_size; (void)in_sizes; (void)n_in; (void)out_size;

    float* h1  = (float*)(ws + o_h1);
    float* hb  = (float*)(ws + o_hb);
    float* hu  = (float*)(ws + o_hu);
    float* z8  = (float*)(ws + o_z8);
    int*   rp  = (int*)(ws + o_rp);
    int*   cnt = (int*)(ws + o_cnt);
    int2*  ev  = (int2*)(ws + o_ev);
    float* Sh  = (float*)(ws + o_Sh);
    float* Sx  = (float*)(ws + o_Sx);
    float* rh  = (float*)(ws + o_rh);
    float* u1  = (float*)(ws + o_u1);
    float* S2  = (float*)(ws + o_S2);
    float* S3c = (float*)(ws + o_S3c);
    float* z2  = (float*)(ws + o_z2);
    float* g2  = (float*)(ws + o_g2);

    // CSR build
    (void)hipMemsetAsync(ws + o_cnt, 0, (size_t)NN * 4, stream);
    hist_kernel<<<(EE + 255) / 256, 256, 0, stream>>>(index, cnt);
    scan_kernel<<<1, 1024, 0, stream>>>(cnt, rp);
    (void)hipMemsetAsync(ws + o_cnt, 0, (size_t)NN * 4, stream);
    scatter_kernel<<<(EE + 255) / 256, 256, 0, stream>>>(index, value, rp, cnt, ev);

    // zero states
    (void)hipMemsetAsync(ws + o_h1, 0, zeroEnd - o_h1, stream);

    for (int t = 0; t < TT; ++t) {
        const float* xt = features + (size_t)t * NN;
        spmm_p1<<<(NN + 3) / 4, 256, 0, stream>>>(rp, ev, h1, xt, Sh, Sx);
        gate1<<<784, 128, 0, stream>>>(Sh, Sx, W1g, b1g, h1, rh, u1);
        spmm64<<<(NN + 3) / 4, 256, 0, stream>>>(rp, ev, rh, S2);
        cand_update<<<1024, 256, 0, stream>>>(S2, Sx, W1c, b1c, u1, h1, W2bg, W2bc, W2ug, W2uc, z8);
        spmm8_gate2<<<(NN * 8 + 255) / 256, 256, 0, stream>>>(rp, ev, z8, hb, hu, W2bg, b2bg, W2ug, b2ug, z2, g2, S3c);
        spmm2_update2<<<(NN * 2 + 255) / 256, 256, 0, stream>>>(rp, ev, z2, S3c, g2, W2bc, b2bc, W2uc, b2uc, hb, hu, z8, out, t);
    }
}

// Round 5
// 8907.655 us; speedup vs baseline: 1.2576x; 1.2244x over previous
//
#include <hip/hip_runtime.h>
#include <math.h>

#define NN 50000
#define EE 800000
#define TT 50

__device__ __forceinline__ float sigm(float x)   { return 1.f / (1.f + __expf(-x)); }
__device__ __forceinline__ float tanh_f(float x) { float e = __expf(2.f * x); return 1.f - 2.f / (e + 1.f); }

// ---------------- CSR build (counting sort by row) ----------------

__global__ __launch_bounds__(256) void hist_kernel(const int* __restrict__ idx, int* __restrict__ cnt) {
    int e = blockIdx.x * blockDim.x + threadIdx.x;
    if (e < EE) atomicAdd(&cnt[idx[2 * e]], 1);
}

__global__ __launch_bounds__(1024) void scan_kernel(const int* __restrict__ cnt, int* __restrict__ rp) {
    __shared__ int part[1024];
    const int PER = (NN + 1023) / 1024;  // 49
    int t = threadIdx.x;
    int base = t * PER;
    int s = 0;
    for (int i = 0; i < PER; ++i) {
        int idx = base + i;
        if (idx < NN) s += cnt[idx];
    }
    part[t] = s;
    __syncthreads();
    int v = s;
    for (int off = 1; off < 1024; off <<= 1) {
        int add = (t >= off) ? part[t - off] : 0;
        __syncthreads();
        v += add;
        part[t] = v;
        __syncthreads();
    }
    int run = v - s;  // exclusive prefix of this thread's chunk
    if (t == 0) rp[0] = 0;
    for (int i = 0; i < PER; ++i) {
        int idx = base + i;
        if (idx < NN) { run += cnt[idx]; rp[idx + 1] = run; }
    }
}

// edge record: .x = col, .y = bit-cast float value
__global__ __launch_bounds__(256) void scatter_kernel(const int* __restrict__ idx, const float* __restrict__ val,
                                                      const int* __restrict__ rp, int* __restrict__ cnt,
                                                      int2* __restrict__ ev) {
    int e = blockIdx.x * blockDim.x + threadIdx.x;
    if (e >= EE) return;
    int r = idx[2 * e];
    int p = rp[r] + atomicAdd(&cnt[r], 1);
    ev[p] = make_int2(idx[2 * e + 1], __float_as_int(val[e]));
}

// ---------------- SpMM kernels (CSR, register-staged edges) ----------------
// Lanes 0..cnt-1 coalesced-load one int2 edge each; (col,val) broadcast via
// __shfl; 4 independent accumulators keep >=4 gathers in flight per wave.

// 65-col pass: writes Sh (N x 64) and Sx (N)
__global__ __launch_bounds__(256) void spmm_p1(const int* __restrict__ rp, const int2* __restrict__ ev,
                                               const float* __restrict__ h, const float* __restrict__ x,
                                               float* __restrict__ Sh, float* __restrict__ Sx) {
    int w = (blockIdx.x * blockDim.x + threadIdx.x) >> 6;
    int lane = threadIdx.x & 63;
    if (w >= NN) return;
    int e0 = rp[w], e1 = rp[w + 1];
    float a0 = 0.f, a1 = 0.f, a2 = 0.f, a3 = 0.f;
    float axp = 0.f;
    for (int eb = e0; eb < e1; eb += 64) {
        int cnt = min(64, e1 - eb);
        int2 p = make_int2(0, 0);
        float xv = 0.f;
        if (lane < cnt) { p = ev[eb + lane]; xv = x[p.x]; }
        axp = fmaf(__int_as_float(p.y), xv, axp);  // x-part: per-lane partial dot
        int k = 0;
        for (; k + 3 < cnt; k += 4) {
            int   c0 = __shfl(p.x, k + 0); float v0 = __int_as_float(__shfl(p.y, k + 0));
            int   c1 = __shfl(p.x, k + 1); float v1 = __int_as_float(__shfl(p.y, k + 1));
            int   c2 = __shfl(p.x, k + 2); float v2 = __int_as_float(__shfl(p.y, k + 2));
            int   c3 = __shfl(p.x, k + 3); float v3 = __int_as_float(__shfl(p.y, k + 3));
            a0 = fmaf(v0, h[(size_t)c0 * 64 + lane], a0);
            a1 = fmaf(v1, h[(size_t)c1 * 64 + lane], a1);
            a2 = fmaf(v2, h[(size_t)c2 * 64 + lane], a2);
            a3 = fmaf(v3, h[(size_t)c3 * 64 + lane], a3);
        }
        for (; k < cnt; ++k) {
            int c = __shfl(p.x, k); float v = __int_as_float(__shfl(p.y, k));
            a0 = fmaf(v, h[(size_t)c * 64 + lane], a0);
        }
    }
    Sh[(size_t)w * 64 + lane] = (a0 + a1) + (a2 + a3);
#pragma unroll
    for (int off = 1; off < 64; off <<= 1) axp += __shfl_xor(axp, off);
    if (lane == 0) Sx[w] = axp;
}

// 64-col pass
__global__ __launch_bounds__(256) void spmm64(const int* __restrict__ rp, const int2* __restrict__ ev,
                                              const float* __restrict__ Xin, float* __restrict__ Sout) {
    int w = (blockIdx.x * blockDim.x + threadIdx.x) >> 6;
    int lane = threadIdx.x & 63;
    if (w >= NN) return;
    int e0 = rp[w], e1 = rp[w + 1];
    float a0 = 0.f, a1 = 0.f, a2 = 0.f, a3 = 0.f;
    for (int eb = e0; eb < e1; eb += 64) {
        int cnt = min(64, e1 - eb);
        int2 p = make_int2(0, 0);
        if (lane < cnt) p = ev[eb + lane];
        int k = 0;
        for (; k + 3 < cnt; k += 4) {
            int   c0 = __shfl(p.x, k + 0); float v0 = __int_as_float(__shfl(p.y, k + 0));
            int   c1 = __shfl(p.x, k + 1); float v1 = __int_as_float(__shfl(p.y, k + 1));
            int   c2 = __shfl(p.x, k + 2); float v2 = __int_as_float(__shfl(p.y, k + 2));
            int   c3 = __shfl(p.x, k + 3); float v3 = __int_as_float(__shfl(p.y, k + 3));
            a0 = fmaf(v0, Xin[(size_t)c0 * 64 + lane], a0);
            a1 = fmaf(v1, Xin[(size_t)c1 * 64 + lane], a1);
            a2 = fmaf(v2, Xin[(size_t)c2 * 64 + lane], a2);
            a3 = fmaf(v3, Xin[(size_t)c3 * 64 + lane], a3);
        }
        for (; k < cnt; ++k) {
            int c = __shfl(p.x, k); float v = __int_as_float(__shfl(p.y, k));
            a0 = fmaf(v, Xin[(size_t)c * 64 + lane], a0);
        }
    }
    Sout[(size_t)w * 64 + lane] = (a0 + a1) + (a2 + a3);
}

// ---------------- Layer-1 dense kernels (unchanged from round 4) ----------------

// ru = sigmoid([Sx|Sh] @ W1_g + b); store rh = r*h1 (fp32) and u (fp32)
#define G1_CHUNK 32
__global__ __launch_bounds__(128) void gate1(const float* __restrict__ Sh, const float* __restrict__ Sx,
                                             const float* __restrict__ Wg, const float* __restrict__ bg,
                                             const float* __restrict__ h1,
                                             float* __restrict__ rh, float* __restrict__ u1) {
    __shared__ float4 s4[G1_CHUNK][16];
    __shared__ float sxl[G1_CHUNK];
    int j = threadIdx.x;  // 0..127 output column
    float w0 = Wg[j];     // row 0 (x part)
    float wk[64];
#pragma unroll
    for (int k = 0; k < 64; ++k) wk[k] = Wg[(1 + k) * 128 + j];
    float bj = bg[j];
    int nChunks = (NN + G1_CHUNK - 1) / G1_CHUNK;
    for (int ch = blockIdx.x; ch < nChunks; ch += gridDim.x) {
        int n0 = ch * G1_CHUNK;
        int nmax = min(G1_CHUNK, NN - n0);
        __syncthreads();
        for (int idx = j; idx < G1_CHUNK * 16; idx += 128) {
            int n = idx >> 4, q = idx & 15;
            if (n < nmax) s4[n][q] = *(const float4*)(Sh + (size_t)(n0 + n) * 64 + q * 4);
        }
        if (j < G1_CHUNK && j < nmax) sxl[j] = Sx[n0 + j];
        __syncthreads();
        for (int n = 0; n < nmax; ++n) {
            float acc = fmaf(sxl[n], w0, bj);
#pragma unroll
            for (int q = 0; q < 16; ++q) {
                float4 sv = s4[n][q];  // broadcast read
                acc = fmaf(sv.x, wk[4 * q + 0], acc);
                acc = fmaf(sv.y, wk[4 * q + 1], acc);
                acc = fmaf(sv.z, wk[4 * q + 2], acc);
                acc = fmaf(sv.w, wk[4 * q + 3], acc);
            }
            float g = sigm(acc);
            int node = n0 + n;
            if (j < 64) rh[node * 64 + j] = g * h1[node * 64 + j];
            else        u1[node * 64 + (j - 64)] = g;
        }
    }
}

// c = tanh([Sx|S2] @ W1_c + b); h1 = u*h1+(1-u)*c; z8[0..5] = h1new @ Wcat
__global__ __launch_bounds__(256) void cand_update(const float* __restrict__ S2, const float* __restrict__ Sx,
                                                   const float* __restrict__ Wc, const float* __restrict__ bc,
                                                   const float* __restrict__ u1, float* __restrict__ h1,
                                                   const float* __restrict__ Wbg, const float* __restrict__ Wbc,
                                                   const float* __restrict__ Wug, const float* __restrict__ Wuc,
                                                   float* __restrict__ z8) {
    int j = threadIdx.x & 63;
    int g = threadIdx.x >> 6;
    float w[65];
#pragma unroll
    for (int k = 0; k < 65; ++k) w[k] = Wc[k * 64 + j];
    float bj = bc[j];
    float wz0 = Wbg[j * 2], wz1 = Wbg[j * 2 + 1], wz2 = Wbc[j];
    float wz3 = Wug[j * 2], wz4 = Wug[j * 2 + 1], wz5 = Wuc[j];
    for (int n = blockIdx.x * 4 + g; n < NN; n += gridDim.x * 4) {
        float acc = fmaf(Sx[n], w[0], bj);
        const float4* s2 = (const float4*)(S2 + n * 64);
#pragma unroll
        for (int q = 0; q < 16; ++q) {
            float4 sv = s2[q];
            acc = fmaf(sv.x, w[1 + 4 * q], acc);
            acc = fmaf(sv.y, w[2 + 4 * q], acc);
            acc = fmaf(sv.z, w[3 + 4 * q], acc);
            acc = fmaf(sv.w, w[4 + 4 * q], acc);
        }
        float c = tanh_f(acc);
        float u = u1[n * 64 + j];
        float ho = h1[n * 64 + j];
        float hn = fmaf(u, ho - c, c);  // u*h + (1-u)*c
        h1[n * 64 + j] = hn;
        float p0 = hn * wz0, p1 = hn * wz1, p2 = hn * wz2;
        float p3 = hn * wz3, p4 = hn * wz4, p5 = hn * wz5;
#pragma unroll
        for (int off = 1; off < 64; off <<= 1) {
            p0 += __shfl_xor(p0, off);
            p1 += __shfl_xor(p1, off);
            p2 += __shfl_xor(p2, off);
            p3 += __shfl_xor(p3, off);
            p4 += __shfl_xor(p4, off);
            p5 += __shfl_xor(p5, off);
        }
        if (j == 0) {
            z8[n * 8 + 0] = p0; z8[n * 8 + 1] = p1; z8[n * 8 + 2] = p2;
            z8[n * 8 + 3] = p3; z8[n * 8 + 4] = p4; z8[n * 8 + 5] = p5;
        }
    }
}

// ---------------- Layer-2 fused kernels (unchanged from round 4) ----------------

__global__ __launch_bounds__(256) void spmm8_gate2(const int* __restrict__ rp, const int2* __restrict__ ev,
                                                   const float* __restrict__ z8,
                                                   const float* __restrict__ hb, const float* __restrict__ hu,
                                                   const float* __restrict__ Wbg, const float* __restrict__ bbg,
                                                   const float* __restrict__ Wug, const float* __restrict__ bug,
                                                   float* __restrict__ z2, float* __restrict__ g2,
                                                   float* __restrict__ S3c) {
    int gid = blockIdx.x * blockDim.x + threadIdx.x;
    int row = gid >> 3;
    int j = gid & 7;
    if (row >= NN) return;
    int e = rp[row], e1 = rp[row + 1];
    float a0 = 0.f, a1 = 0.f;
    for (; e + 1 < e1; e += 2) {
        int2 p0 = ev[e], p1 = ev[e + 1];
        a0 = fmaf(__int_as_float(p0.y), z8[p0.x * 8 + j], a0);
        a1 = fmaf(__int_as_float(p1.y), z8[p1.x * 8 + j], a1);
    }
    if (e < e1) { int2 p = ev[e]; a0 = fmaf(__int_as_float(p.y), z8[p.x * 8 + j], a0); }
    float s = a0 + a1;
    if (j == 2) S3c[row * 2 + 0] = s;
    if (j == 5) S3c[row * 2 + 1] = s;
    int lane = threadIdx.x & 63;
    int base = lane & ~7;
    float s0 = __shfl(s, base + 0);
    float s1 = __shfl(s, base + 1);
    float s3 = __shfl(s, base + 3);
    float s4 = __shfl(s, base + 4);
    float s6 = __shfl(s, base + 6);
    float s7 = __shfl(s, base + 7);
    if (j == 0) {
        float rb = sigm(fmaf(s6, Wbg[128], s0) + bbg[0]);
        float ub = sigm(fmaf(s6, Wbg[129], s1) + bbg[1]);
        float ru = sigm(fmaf(s7, Wug[128], s3) + bug[0]);
        float uu = sigm(fmaf(s7, Wug[129], s4) + bug[1]);
        z2[row * 2 + 0] = rb * hb[row];
        z2[row * 2 + 1] = ru * hu[row];
        g2[row * 2 + 0] = ub;
        g2[row * 2 + 1] = uu;
    }
}

__global__ __launch_bounds__(256) void spmm2_update2(const int* __restrict__ rp, const int2* __restrict__ ev,
                                                     const float* __restrict__ z2,
                                                     const float* __restrict__ S3c, const float* __restrict__ g2,
                                                     const float* __restrict__ Wbc, const float* __restrict__ bbc,
                                                     const float* __restrict__ Wuc, const float* __restrict__ buc,
                                                     float* __restrict__ hb, float* __restrict__ hu,
                                                     float* __restrict__ z8, float* __restrict__ out, int t) {
    int gid = blockIdx.x * blockDim.x + threadIdx.x;
    int row = gid >> 1;
    int j = gid & 1;
    if (row >= NN) return;
    int e = rp[row], e1 = rp[row + 1];
    float a0 = 0.f, a1 = 0.f;
    for (; e + 1 < e1; e += 2) {
        int2 p0 = ev[e], p1 = ev[e + 1];
        a0 = fmaf(__int_as_float(p0.y), z2[p0.x * 2 + j], a0);
        a1 = fmaf(__int_as_float(p1.y), z2[p1.x * 2 + j], a1);
    }
    if (e < e1) { int2 p = ev[e]; a0 = fmaf(__int_as_float(p.y), z2[p.x * 2 + j], a0); }
    float s = a0 + a1;
    int lane = threadIdx.x & 63;
    int base = lane & ~1;
    float sA = __shfl(s, base + 0);
    float sB = __shfl(s, base + 1);
    if (j == 0) {
        float cb = tanh_f(fmaf(sA, Wbc[64], S3c[row * 2 + 0]) + bbc[0]);
        float cu = tanh_f(fmaf(sB, Wuc[64], S3c[row * 2 + 1]) + buc[0]);
        float ub = g2[row * 2 + 0], uu = g2[row * 2 + 1];
        float hbn = fmaf(ub, hb[row] - cb, cb);
        float hun = fmaf(uu, hu[row] - cu, cu);
        hb[row] = hbn; hu[row] = hun;
        z8[row * 8 + 6] = hbn;
        z8[row * 8 + 7] = hun;
        out[(size_t)t * NN + row] = hbn;
        out[(size_t)(TT + t) * NN + row] = hun;
    }
}

// ---------------- host ----------------

extern "C" void kernel_launch(void* const* d_in, const int* in_sizes, int n_in,
                              void* d_out, int out_size, void* d_ws, size_t ws_size,
                              hipStream_t stream) {
    const float* features = (const float*)d_in[0];
    const int*   index    = (const int*)d_in[1];
    const float* value    = (const float*)d_in[2];
    const float* W1g  = (const float*)d_in[3];
    const float* b1g  = (const float*)d_in[4];
    const float* W1c  = (const float*)d_in[5];
    const float* b1c  = (const float*)d_in[6];
    const float* W2bg = (const float*)d_in[7];
    const float* b2bg = (const float*)d_in[8];
    const float* W2bc = (const float*)d_in[9];
    const float* b2bc = (const float*)d_in[10];
    const float* W2ug = (const float*)d_in[11];
    const float* b2ug = (const float*)d_in[12];
    const float* W2uc = (const float*)d_in[13];
    const float* b2uc = (const float*)d_in[14];
    float* out = (float*)d_out;

    char* ws = (char*)d_ws;
    size_t o = 0;
    auto alloc = [&](size_t bytes) { size_t cur = o; o += (bytes + 255) & ~(size_t)255; return cur; };
    // zero-init region: h1, hb, hu, z8 (contiguous)
    size_t o_h1  = alloc((size_t)NN * 64 * 4);
    size_t o_hb  = alloc((size_t)NN * 4);
    size_t o_hu  = alloc((size_t)NN * 4);
    size_t o_z8  = alloc((size_t)NN * 8 * 4);
    size_t zeroEnd = o;
    size_t o_rp  = alloc((size_t)(NN + 1) * 4);
    size_t o_cnt = alloc((size_t)NN * 4);
    size_t o_ev  = alloc((size_t)EE * 8);
    size_t o_Sh  = alloc((size_t)NN * 64 * 4);
    size_t o_Sx  = alloc((size_t)NN * 4);
    size_t o_rh  = alloc((size_t)NN * 64 * 4);
    size_t o_u1  = alloc((size_t)NN * 64 * 4);
    size_t o_S2  = alloc((size_t)NN * 64 * 4);
    size_t o_S3c = alloc((size_t)NN * 2 * 4);
    size_t o_z2  = alloc((size_t)NN * 2 * 4);
    size_t o_g2  = alloc((size_t)NN * 2 * 4);
    (void)ws_size; (void)in_sizes; (void)n_in; (void)out_size;

    float* h1  = (float*)(ws + o_h1);
    float* hb  = (float*)(ws + o_hb);
    float* hu  = (float*)(ws + o_hu);
    float* z8  = (float*)(ws + o_z8);
    int*   rp  = (int*)(ws + o_rp);
    int*   cnt = (int*)(ws + o_cnt);
    int2*  ev  = (int2*)(ws + o_ev);
    float* Sh  = (float*)(ws + o_Sh);
    float* Sx  = (float*)(ws + o_Sx);
    float* rh  = (float*)(ws + o_rh);
    float* u1  = (float*)(ws + o_u1);
    float* S2  = (float*)(ws + o_S2);
    float* S3c = (float*)(ws + o_S3c);
    float* z2  = (float*)(ws + o_z2);
    float* g2  = (float*)(ws + o_g2);

    // CSR build
    (void)hipMemsetAsync(ws + o_cnt, 0, (size_t)NN * 4, stream);
    hist_kernel<<<(EE + 255) / 256, 256, 0, stream>>>(index, cnt);
    scan_kernel<<<1, 1024, 0, stream>>>(cnt, rp);
    (void)hipMemsetAsync(ws + o_cnt, 0, (size_t)NN * 4, stream);
    scatter_kernel<<<(EE + 255) / 256, 256, 0, stream>>>(index, value, rp, cnt, ev);

    // zero states
    (void)hipMemsetAsync(ws + o_h1, 0, zeroEnd - o_h1, stream);

    for (int t = 0; t < TT; ++t) {
        const float* xt = features + (size_t)t * NN;
        spmm_p1<<<(NN + 3) / 4, 256, 0, stream>>>(rp, ev, h1, xt, Sh, Sx);
        gate1<<<784, 128, 0, stream>>>(Sh, Sx, W1g, b1g, h1, rh, u1);
        spmm64<<<(NN + 3) / 4, 256, 0, stream>>>(rp, ev, rh, S2);
        cand_update<<<1024, 256, 0, stream>>>(S2, Sx, W1c, b1c, u1, h1, W2bg, W2bc, W2ug, W2uc, z8);
        spmm8_gate2<<<(NN * 8 + 255) / 256, 256, 0, stream>>>(rp, ev, z8, hb, hu, W2bg, b2bg, W2ug, b2ug, z2, g2, S3c);
        spmm2_update2<<<(NN * 2 + 255) / 256, 256, 0, stream>>>(rp, ev, z2, S3c, g2, W2bc, b2bc, W2uc, b2uc, hb, hu, z8, out, t);
    }
}

// Round 6
// 7904.181 us; speedup vs baseline: 1.4173x; 1.1270x over previous
//
#include <hip/hip_runtime.h>
#include <math.h>

#define NN 50000
#define EE 800000
#define TT 50

__device__ __forceinline__ float sigm(float x)   { return 1.f / (1.f + __expf(-x)); }
__device__ __forceinline__ float tanh_f(float x) { float e = __expf(2.f * x); return 1.f - 2.f / (e + 1.f); }

// ---------------- CSR build (counting sort by row) ----------------

__global__ __launch_bounds__(256) void hist_kernel(const int* __restrict__ idx, int* __restrict__ cnt) {
    int e = blockIdx.x * blockDim.x + threadIdx.x;
    if (e < EE) atomicAdd(&cnt[idx[2 * e]], 1);
}

__global__ __launch_bounds__(1024) void scan_kernel(const int* __restrict__ cnt, int* __restrict__ rp) {
    __shared__ int part[1024];
    const int PER = (NN + 1023) / 1024;  // 49
    int t = threadIdx.x;
    int base = t * PER;
    int s = 0;
    for (int i = 0; i < PER; ++i) {
        int idx = base + i;
        if (idx < NN) s += cnt[idx];
    }
    part[t] = s;
    __syncthreads();
    int v = s;
    for (int off = 1; off < 1024; off <<= 1) {
        int add = (t >= off) ? part[t - off] : 0;
        __syncthreads();
        v += add;
        part[t] = v;
        __syncthreads();
    }
    int run = v - s;  // exclusive prefix of this thread's chunk
    if (t == 0) rp[0] = 0;
    for (int i = 0; i < PER; ++i) {
        int idx = base + i;
        if (idx < NN) { run += cnt[idx]; rp[idx + 1] = run; }
    }
}

// edge record: .x = col, .y = bit-cast float value
__global__ __launch_bounds__(256) void scatter_kernel(const int* __restrict__ idx, const float* __restrict__ val,
                                                      const int* __restrict__ rp, int* __restrict__ cnt,
                                                      int2* __restrict__ ev) {
    int e = blockIdx.x * blockDim.x + threadIdx.x;
    if (e >= EE) return;
    int r = idx[2 * e];
    int p = rp[r] + atomicAdd(&cnt[r], 1);
    ev[p] = make_int2(idx[2 * e + 1], __float_as_int(val[e]));
}

// ---------------- SpMM kernels (CSR, scalar edge stream) ----------------
// Row index w is wave-uniform -> rp[w] and ev[e] are scalar (s_load) streams;
// edge (col,val) live in SGPRs, broadcast free. 8 independent accumulators
// keep 8 row-gathers (256B each) in flight per wave.

// 65-col pass: writes Sh (N x 64) and Sx (N)
__global__ __launch_bounds__(256) void spmm_p1(const int* __restrict__ rp, const int2* __restrict__ ev,
                                               const float* __restrict__ h, const float* __restrict__ x,
                                               float* __restrict__ Sh, float* __restrict__ Sx) {
    int w = __builtin_amdgcn_readfirstlane((blockIdx.x * blockDim.x + threadIdx.x) >> 6);
    int lane = threadIdx.x & 63;
    if (w >= NN) return;
    int e0 = __builtin_amdgcn_readfirstlane(rp[w]);
    int e1 = __builtin_amdgcn_readfirstlane(rp[w + 1]);
    const float* hl = h + lane;
    float a0 = 0.f, a1 = 0.f, a2 = 0.f, a3 = 0.f, a4 = 0.f, a5 = 0.f, a6 = 0.f, a7 = 0.f;
    float ax = 0.f;  // uniform across wave
    int e = e0;
    for (; e + 8 <= e1; e += 8) {
        int2 q0 = ev[e + 0], q1 = ev[e + 1], q2 = ev[e + 2], q3 = ev[e + 3];
        int2 q4 = ev[e + 4], q5 = ev[e + 5], q6 = ev[e + 6], q7 = ev[e + 7];
        float v0 = __int_as_float(q0.y), v1 = __int_as_float(q1.y);
        float v2 = __int_as_float(q2.y), v3 = __int_as_float(q3.y);
        float v4 = __int_as_float(q4.y), v5 = __int_as_float(q5.y);
        float v6 = __int_as_float(q6.y), v7 = __int_as_float(q7.y);
        a0 = fmaf(v0, hl[(size_t)q0.x * 64], a0);
        a1 = fmaf(v1, hl[(size_t)q1.x * 64], a1);
        a2 = fmaf(v2, hl[(size_t)q2.x * 64], a2);
        a3 = fmaf(v3, hl[(size_t)q3.x * 64], a3);
        a4 = fmaf(v4, hl[(size_t)q4.x * 64], a4);
        a5 = fmaf(v5, hl[(size_t)q5.x * 64], a5);
        a6 = fmaf(v6, hl[(size_t)q6.x * 64], a6);
        a7 = fmaf(v7, hl[(size_t)q7.x * 64], a7);
        ax = fmaf(v0, x[q0.x], ax); ax = fmaf(v1, x[q1.x], ax);
        ax = fmaf(v2, x[q2.x], ax); ax = fmaf(v3, x[q3.x], ax);
        ax = fmaf(v4, x[q4.x], ax); ax = fmaf(v5, x[q5.x], ax);
        ax = fmaf(v6, x[q6.x], ax); ax = fmaf(v7, x[q7.x], ax);
    }
    for (; e < e1; ++e) {
        int2 q = ev[e];
        float v = __int_as_float(q.y);
        a0 = fmaf(v, hl[(size_t)q.x * 64], a0);
        ax = fmaf(v, x[q.x], ax);
    }
    Sh[(size_t)w * 64 + lane] = ((a0 + a1) + (a2 + a3)) + ((a4 + a5) + (a6 + a7));
    if (lane == 0) Sx[w] = ax;
}

// 64-col pass
__global__ __launch_bounds__(256) void spmm64(const int* __restrict__ rp, const int2* __restrict__ ev,
                                              const float* __restrict__ Xin, float* __restrict__ Sout) {
    int w = __builtin_amdgcn_readfirstlane((blockIdx.x * blockDim.x + threadIdx.x) >> 6);
    int lane = threadIdx.x & 63;
    if (w >= NN) return;
    int e0 = __builtin_amdgcn_readfirstlane(rp[w]);
    int e1 = __builtin_amdgcn_readfirstlane(rp[w + 1]);
    const float* xl = Xin + lane;
    float a0 = 0.f, a1 = 0.f, a2 = 0.f, a3 = 0.f, a4 = 0.f, a5 = 0.f, a6 = 0.f, a7 = 0.f;
    int e = e0;
    for (; e + 8 <= e1; e += 8) {
        int2 q0 = ev[e + 0], q1 = ev[e + 1], q2 = ev[e + 2], q3 = ev[e + 3];
        int2 q4 = ev[e + 4], q5 = ev[e + 5], q6 = ev[e + 6], q7 = ev[e + 7];
        a0 = fmaf(__int_as_float(q0.y), xl[(size_t)q0.x * 64], a0);
        a1 = fmaf(__int_as_float(q1.y), xl[(size_t)q1.x * 64], a1);
        a2 = fmaf(__int_as_float(q2.y), xl[(size_t)q2.x * 64], a2);
        a3 = fmaf(__int_as_float(q3.y), xl[(size_t)q3.x * 64], a3);
        a4 = fmaf(__int_as_float(q4.y), xl[(size_t)q4.x * 64], a4);
        a5 = fmaf(__int_as_float(q5.y), xl[(size_t)q5.x * 64], a5);
        a6 = fmaf(__int_as_float(q6.y), xl[(size_t)q6.x * 64], a6);
        a7 = fmaf(__int_as_float(q7.y), xl[(size_t)q7.x * 64], a7);
    }
    for (; e < e1; ++e) {
        int2 q = ev[e];
        a0 = fmaf(__int_as_float(q.y), xl[(size_t)q.x * 64], a0);
    }
    Sout[(size_t)w * 64 + lane] = ((a0 + a1) + (a2 + a3)) + ((a4 + a5) + (a6 + a7));
}

// ---------------- Layer-1 dense kernels ----------------

// ru = sigmoid([Sx|Sh] @ W1_g + b); store rh = r*h1 (fp32) and u (fp32)
#define G1_CHUNK 32
__global__ __launch_bounds__(128) void gate1(const float* __restrict__ Sh, const float* __restrict__ Sx,
                                             const float* __restrict__ Wg, const float* __restrict__ bg,
                                             const float* __restrict__ h1,
                                             float* __restrict__ rh, float* __restrict__ u1) {
    __shared__ float4 s4[G1_CHUNK][16];
    __shared__ float sxl[G1_CHUNK];
    int j = threadIdx.x;  // 0..127 output column
    float w0 = Wg[j];     // row 0 (x part)
    float wk[64];
#pragma unroll
    for (int k = 0; k < 64; ++k) wk[k] = Wg[(1 + k) * 128 + j];
    float bj = bg[j];
    int nChunks = (NN + G1_CHUNK - 1) / G1_CHUNK;
    for (int ch = blockIdx.x; ch < nChunks; ch += gridDim.x) {
        int n0 = ch * G1_CHUNK;
        int nmax = min(G1_CHUNK, NN - n0);
        __syncthreads();
        for (int idx = j; idx < G1_CHUNK * 16; idx += 128) {
            int n = idx >> 4, q = idx & 15;
            if (n < nmax) s4[n][q] = *(const float4*)(Sh + (size_t)(n0 + n) * 64 + q * 4);
        }
        if (j < G1_CHUNK && j < nmax) sxl[j] = Sx[n0 + j];
        __syncthreads();
        for (int n = 0; n < nmax; ++n) {
            float acc = fmaf(sxl[n], w0, bj);
#pragma unroll
            for (int q = 0; q < 16; ++q) {
                float4 sv = s4[n][q];  // broadcast read
                acc = fmaf(sv.x, wk[4 * q + 0], acc);
                acc = fmaf(sv.y, wk[4 * q + 1], acc);
                acc = fmaf(sv.z, wk[4 * q + 2], acc);
                acc = fmaf(sv.w, wk[4 * q + 3], acc);
            }
            float g = sigm(acc);
            int node = n0 + n;
            if (j < 64) rh[node * 64 + j] = g * h1[node * 64 + j];
            else        u1[node * 64 + (j - 64)] = g;
        }
    }
}

// c = tanh([Sx|S2] @ W1_c + b); h1 = u*h1+(1-u)*c; z8[0..5] = h1new @ Wcat
__global__ __launch_bounds__(256) void cand_update(const float* __restrict__ S2, const float* __restrict__ Sx,
                                                   const float* __restrict__ Wc, const float* __restrict__ bc,
                                                   const float* __restrict__ u1, float* __restrict__ h1,
                                                   const float* __restrict__ Wbg, const float* __restrict__ Wbc,
                                                   const float* __restrict__ Wug, const float* __restrict__ Wuc,
                                                   float* __restrict__ z8) {
    int j = threadIdx.x & 63;
    int g = threadIdx.x >> 6;
    float w[65];
#pragma unroll
    for (int k = 0; k < 65; ++k) w[k] = Wc[k * 64 + j];
    float bj = bc[j];
    float wz0 = Wbg[j * 2], wz1 = Wbg[j * 2 + 1], wz2 = Wbc[j];
    float wz3 = Wug[j * 2], wz4 = Wug[j * 2 + 1], wz5 = Wuc[j];
    for (int n = blockIdx.x * 4 + g; n < NN; n += gridDim.x * 4) {
        float acc = fmaf(Sx[n], w[0], bj);
        const float4* s2 = (const float4*)(S2 + n * 64);
#pragma unroll
        for (int q = 0; q < 16; ++q) {
            float4 sv = s2[q];
            acc = fmaf(sv.x, w[1 + 4 * q], acc);
            acc = fmaf(sv.y, w[2 + 4 * q], acc);
            acc = fmaf(sv.z, w[3 + 4 * q], acc);
            acc = fmaf(sv.w, w[4 + 4 * q], acc);
        }
        float c = tanh_f(acc);
        float u = u1[n * 64 + j];
        float ho = h1[n * 64 + j];
        float hn = fmaf(u, ho - c, c);  // u*h + (1-u)*c
        h1[n * 64 + j] = hn;
        float p0 = hn * wz0, p1 = hn * wz1, p2 = hn * wz2;
        float p3 = hn * wz3, p4 = hn * wz4, p5 = hn * wz5;
#pragma unroll
        for (int off = 1; off < 64; off <<= 1) {
            p0 += __shfl_xor(p0, off);
            p1 += __shfl_xor(p1, off);
            p2 += __shfl_xor(p2, off);
            p3 += __shfl_xor(p3, off);
            p4 += __shfl_xor(p4, off);
            p5 += __shfl_xor(p5, off);
        }
        if (j == 0) {
            z8[n * 8 + 0] = p0; z8[n * 8 + 1] = p1; z8[n * 8 + 2] = p2;
            z8[n * 8 + 3] = p3; z8[n * 8 + 4] = p4; z8[n * 8 + 5] = p5;
        }
    }
}

// ---------------- Layer-2 fused kernels ----------------

__global__ __launch_bounds__(256) void spmm8_gate2(const int* __restrict__ rp, const int2* __restrict__ ev,
                                                   const float* __restrict__ z8,
                                                   const float* __restrict__ hb, const float* __restrict__ hu,
                                                   const float* __restrict__ Wbg, const float* __restrict__ bbg,
                                                   const float* __restrict__ Wug, const float* __restrict__ bug,
                                                   float* __restrict__ z2, float* __restrict__ g2,
                                                   float* __restrict__ S3c) {
    int gid = blockIdx.x * blockDim.x + threadIdx.x;
    int row = gid >> 3;
    int j = gid & 7;
    if (row >= NN) return;
    int e = rp[row], e1 = rp[row + 1];
    float a0 = 0.f, a1 = 0.f, a2 = 0.f, a3 = 0.f;
    for (; e + 3 < e1; e += 4) {
        int2 p0 = ev[e], p1 = ev[e + 1], p2 = ev[e + 2], p3 = ev[e + 3];
        a0 = fmaf(__int_as_float(p0.y), z8[(size_t)p0.x * 8 + j], a0);
        a1 = fmaf(__int_as_float(p1.y), z8[(size_t)p1.x * 8 + j], a1);
        a2 = fmaf(__int_as_float(p2.y), z8[(size_t)p2.x * 8 + j], a2);
        a3 = fmaf(__int_as_float(p3.y), z8[(size_t)p3.x * 8 + j], a3);
    }
    for (; e < e1; ++e) {
        int2 p = ev[e];
        a0 = fmaf(__int_as_float(p.y), z8[(size_t)p.x * 8 + j], a0);
    }
    float s = (a0 + a1) + (a2 + a3);
    if (j == 2) S3c[row * 2 + 0] = s;
    if (j == 5) S3c[row * 2 + 1] = s;
    int lane = threadIdx.x & 63;
    int base = lane & ~7;
    float s0 = __shfl(s, base + 0);
    float s1 = __shfl(s, base + 1);
    float s3 = __shfl(s, base + 3);
    float s4 = __shfl(s, base + 4);
    float s6 = __shfl(s, base + 6);
    float s7 = __shfl(s, base + 7);
    if (j == 0) {
        float rb = sigm(fmaf(s6, Wbg[128], s0) + bbg[0]);
        float ub = sigm(fmaf(s6, Wbg[129], s1) + bbg[1]);
        float ru = sigm(fmaf(s7, Wug[128], s3) + bug[0]);
        float uu = sigm(fmaf(s7, Wug[129], s4) + bug[1]);
        z2[row * 2 + 0] = rb * hb[row];
        z2[row * 2 + 1] = ru * hu[row];
        g2[row * 2 + 0] = ub;
        g2[row * 2 + 1] = uu;
    }
}

__global__ __launch_bounds__(256) void spmm2_update2(const int* __restrict__ rp, const int2* __restrict__ ev,
                                                     const float* __restrict__ z2,
                                                     const float* __restrict__ S3c, const float* __restrict__ g2,
                                                     const float* __restrict__ Wbc, const float* __restrict__ bbc,
                                                     const float* __restrict__ Wuc, const float* __restrict__ buc,
                                                     float* __restrict__ hb, float* __restrict__ hu,
                                                     float* __restrict__ z8, float* __restrict__ out, int t) {
    int gid = blockIdx.x * blockDim.x + threadIdx.x;
    int row = gid >> 1;
    int j = gid & 1;
    if (row >= NN) return;
    int e = rp[row], e1 = rp[row + 1];
    float a0 = 0.f, a1 = 0.f, a2 = 0.f, a3 = 0.f;
    for (; e + 3 < e1; e += 4) {
        int2 p0 = ev[e], p1 = ev[e + 1], p2 = ev[e + 2], p3 = ev[e + 3];
        a0 = fmaf(__int_as_float(p0.y), z2[(size_t)p0.x * 2 + j], a0);
        a1 = fmaf(__int_as_float(p1.y), z2[(size_t)p1.x * 2 + j], a1);
        a2 = fmaf(__int_as_float(p2.y), z2[(size_t)p2.x * 2 + j], a2);
        a3 = fmaf(__int_as_float(p3.y), z2[(size_t)p3.x * 2 + j], a3);
    }
    for (; e < e1; ++e) {
        int2 p = ev[e];
        a0 = fmaf(__int_as_float(p.y), z2[(size_t)p.x * 2 + j], a0);
    }
    float s = (a0 + a1) + (a2 + a3);
    int lane = threadIdx.x & 63;
    int base = lane & ~1;
    float sA = __shfl(s, base + 0);
    float sB = __shfl(s, base + 1);
    if (j == 0) {
        float cb = tanh_f(fmaf(sA, Wbc[64], S3c[row * 2 + 0]) + bbc[0]);
        float cu = tanh_f(fmaf(sB, Wuc[64], S3c[row * 2 + 1]) + buc[0]);
        float ub = g2[row * 2 + 0], uu = g2[row * 2 + 1];
        float hbn = fmaf(ub, hb[row] - cb, cb);
        float hun = fmaf(uu, hu[row] - cu, cu);
        hb[row] = hbn; hu[row] = hun;
        z8[row * 8 + 6] = hbn;
        z8[row * 8 + 7] = hun;
        out[(size_t)t * NN + row] = hbn;
        out[(size_t)(TT + t) * NN + row] = hun;
    }
}

// ---------------- host ----------------

extern "C" void kernel_launch(void* const* d_in, const int* in_sizes, int n_in,
                              void* d_out, int out_size, void* d_ws, size_t ws_size,
                              hipStream_t stream) {
    const float* features = (const float*)d_in[0];
    const int*   index    = (const int*)d_in[1];
    const float* value    = (const float*)d_in[2];
    const float* W1g  = (const float*)d_in[3];
    const float* b1g  = (const float*)d_in[4];
    const float* W1c  = (const float*)d_in[5];
    const float* b1c  = (const float*)d_in[6];
    const float* W2bg = (const float*)d_in[7];
    const float* b2bg = (const float*)d_in[8];
    const float* W2bc = (const float*)d_in[9];
    const float* b2bc = (const float*)d_in[10];
    const float* W2ug = (const float*)d_in[11];
    const float* b2ug = (const float*)d_in[12];
    const float* W2uc = (const float*)d_in[13];
    const float* b2uc = (const float*)d_in[14];
    float* out = (float*)d_out;

    char* ws = (char*)d_ws;
    size_t o = 0;
    auto alloc = [&](size_t bytes) { size_t cur = o; o += (bytes + 255) & ~(size_t)255; return cur; };
    // zero-init region: h1, hb, hu, z8 (contiguous)
    size_t o_h1  = alloc((size_t)NN * 64 * 4);
    size_t o_hb  = alloc((size_t)NN * 4);
    size_t o_hu  = alloc((size_t)NN * 4);
    size_t o_z8  = alloc((size_t)NN * 8 * 4);
    size_t zeroEnd = o;
    size_t o_rp  = alloc((size_t)(NN + 1) * 4);
    size_t o_cnt = alloc((size_t)NN * 4);
    size_t o_ev  = alloc((size_t)EE * 8);
    size_t o_Sh  = alloc((size_t)NN * 64 * 4);
    size_t o_Sx  = alloc((size_t)NN * 4);
    size_t o_rh  = alloc((size_t)NN * 64 * 4);
    size_t o_u1  = alloc((size_t)NN * 64 * 4);
    size_t o_S2  = alloc((size_t)NN * 64 * 4);
    size_t o_S3c = alloc((size_t)NN * 2 * 4);
    size_t o_z2  = alloc((size_t)NN * 2 * 4);
    size_t o_g2  = alloc((size_t)NN * 2 * 4);
    (void)ws_size; (void)in_sizes; (void)n_in; (void)out_size;

    float* h1  = (float*)(ws + o_h1);
    float* hb  = (float*)(ws + o_hb);
    float* hu  = (float*)(ws + o_hu);
    float* z8  = (float*)(ws + o_z8);
    int*   rp  = (int*)(ws + o_rp);
    int*   cnt = (int*)(ws + o_cnt);
    int2*  ev  = (int2*)(ws + o_ev);
    float* Sh  = (float*)(ws + o_Sh);
    float* Sx  = (float*)(ws + o_Sx);
    float* rh  = (float*)(ws + o_rh);
    float* u1  = (float*)(ws + o_u1);
    float* S2  = (float*)(ws + o_S2);
    float* S3c = (float*)(ws + o_S3c);
    float* z2  = (float*)(ws + o_z2);
    float* g2  = (float*)(ws + o_g2);

    // CSR build
    (void)hipMemsetAsync(ws + o_cnt, 0, (size_t)NN * 4, stream);
    hist_kernel<<<(EE + 255) / 256, 256, 0, stream>>>(index, cnt);
    scan_kernel<<<1, 1024, 0, stream>>>(cnt, rp);
    (void)hipMemsetAsync(ws + o_cnt, 0, (size_t)NN * 4, stream);
    scatter_kernel<<<(EE + 255) / 256, 256, 0, stream>>>(index, value, rp, cnt, ev);

    // zero states
    (void)hipMemsetAsync(ws + o_h1, 0, zeroEnd - o_h1, stream);

    const int nChunks = (NN + G1_CHUNK - 1) / G1_CHUNK;  // 1563
    for (int t = 0; t < TT; ++t) {
        const float* xt = features + (size_t)t * NN;
        spmm_p1<<<(NN + 3) / 4, 256, 0, stream>>>(rp, ev, h1, xt, Sh, Sx);
        gate1<<<nChunks, 128, 0, stream>>>(Sh, Sx, W1g, b1g, h1, rh, u1);
        spmm64<<<(NN + 3) / 4, 256, 0, stream>>>(rp, ev, rh, S2);
        cand_update<<<1024, 256, 0, stream>>>(S2, Sx, W1c, b1c, u1, h1, W2bg, W2bc, W2ug, W2uc, z8);
        spmm8_gate2<<<(NN * 8 + 255) / 256, 256, 0, stream>>>(rp, ev, z8, hb, hu, W2bg, b2bg, W2ug, b2ug, z2, g2, S3c);
        spmm2_update2<<<(NN * 2 + 255) / 256, 256, 0, stream>>>(rp, ev, z2, S3c, g2, W2bc, b2bc, W2uc, b2uc, hb, hu, z8, out, t);
    }
}

// Round 7
// 7534.487 us; speedup vs baseline: 1.4868x; 1.0491x over previous
//
#include <hip/hip_runtime.h>
#include <math.h>

#define NN 50000
#define EE 800000
#define TT 50

__device__ __forceinline__ float sigm(float x)   { return 1.f / (1.f + __expf(-x)); }
__device__ __forceinline__ float tanh_f(float x) { float e = __expf(2.f * x); return 1.f - 2.f / (e + 1.f); }

// ---------------- CSR build (counting sort by row) ----------------

__global__ __launch_bounds__(256) void hist_kernel(const int* __restrict__ idx, int* __restrict__ cnt) {
    int e = blockIdx.x * blockDim.x + threadIdx.x;
    if (e < EE) atomicAdd(&cnt[idx[2 * e]], 1);
}

__global__ __launch_bounds__(1024) void scan_kernel(const int* __restrict__ cnt, int* __restrict__ rp) {
    __shared__ int part[1024];
    const int PER = (NN + 1023) / 1024;  // 49
    int t = threadIdx.x;
    int base = t * PER;
    int s = 0;
    for (int i = 0; i < PER; ++i) {
        int idx = base + i;
        if (idx < NN) s += cnt[idx];
    }
    part[t] = s;
    __syncthreads();
    int v = s;
    for (int off = 1; off < 1024; off <<= 1) {
        int add = (t >= off) ? part[t - off] : 0;
        __syncthreads();
        v += add;
        part[t] = v;
        __syncthreads();
    }
    int run = v - s;  // exclusive prefix of this thread's chunk
    if (t == 0) rp[0] = 0;
    for (int i = 0; i < PER; ++i) {
        int idx = base + i;
        if (idx < NN) { run += cnt[idx]; rp[idx + 1] = run; }
    }
}

// edge record: .x = col, .y = bit-cast float value
__global__ __launch_bounds__(256) void scatter_kernel(const int* __restrict__ idx, const float* __restrict__ val,
                                                      const int* __restrict__ rp, int* __restrict__ cnt,
                                                      int2* __restrict__ ev) {
    int e = blockIdx.x * blockDim.x + threadIdx.x;
    if (e >= EE) return;
    int r = idx[2 * e];
    int p = rp[r] + atomicAdd(&cnt[r], 1);
    ev[p] = make_int2(idx[2 * e + 1], __float_as_int(val[e]));
}

// ---------------- one-time x precompute ----------------

// features (T x N) -> xT (N x 64), t in [50,64) zero-padded
__global__ __launch_bounds__(256) void transpose_x(const float* __restrict__ F, float* __restrict__ xT) {
    __shared__ float tile[64][51];
    int n0 = blockIdx.x * 64;
    for (int i = threadIdx.x; i < TT * 64; i += 256) {
        int t = i >> 6, n = i & 63;
        if (n0 + n < NN) tile[n][t] = F[(size_t)t * NN + n0 + n];
    }
    __syncthreads();
    for (int i = threadIdx.x; i < 64 * 64; i += 256) {
        int n = i >> 6, t = i & 63;
        if (n0 + n < NN) xT[(size_t)(n0 + n) * 64 + t] = (t < TT) ? tile[n][t] : 0.f;
    }
}

// SxAll[t][w] = sum_e v_e * xT[col_e][t]  (one pass for all 50 steps)
__global__ __launch_bounds__(256) void spmm_sx(const int* __restrict__ rp, const int2* __restrict__ ev,
                                               const float* __restrict__ xT, float* __restrict__ SxAll) {
    int w = __builtin_amdgcn_readfirstlane((blockIdx.x * blockDim.x + threadIdx.x) >> 6);
    int lane = threadIdx.x & 63;
    if (w >= NN) return;
    int e0 = __builtin_amdgcn_readfirstlane(rp[w]);
    int e1 = __builtin_amdgcn_readfirstlane(rp[w + 1]);
    const float* xl = xT + lane;
    float a0 = 0.f, a1 = 0.f, a2 = 0.f, a3 = 0.f, a4 = 0.f, a5 = 0.f, a6 = 0.f, a7 = 0.f;
    int e = e0;
    for (; e + 8 <= e1; e += 8) {
        int2 q0 = ev[e + 0], q1 = ev[e + 1], q2 = ev[e + 2], q3 = ev[e + 3];
        int2 q4 = ev[e + 4], q5 = ev[e + 5], q6 = ev[e + 6], q7 = ev[e + 7];
        a0 = fmaf(__int_as_float(q0.y), xl[(size_t)q0.x * 64], a0);
        a1 = fmaf(__int_as_float(q1.y), xl[(size_t)q1.x * 64], a1);
        a2 = fmaf(__int_as_float(q2.y), xl[(size_t)q2.x * 64], a2);
        a3 = fmaf(__int_as_float(q3.y), xl[(size_t)q3.x * 64], a3);
        a4 = fmaf(__int_as_float(q4.y), xl[(size_t)q4.x * 64], a4);
        a5 = fmaf(__int_as_float(q5.y), xl[(size_t)q5.x * 64], a5);
        a6 = fmaf(__int_as_float(q6.y), xl[(size_t)q6.x * 64], a6);
        a7 = fmaf(__int_as_float(q7.y), xl[(size_t)q7.x * 64], a7);
    }
    for (; e < e1; ++e) {
        int2 q = ev[e];
        a0 = fmaf(__int_as_float(q.y), xl[(size_t)q.x * 64], a0);
    }
    float s = ((a0 + a1) + (a2 + a3)) + ((a4 + a5) + (a6 + a7));
    if (lane < TT) SxAll[(size_t)lane * NN + w] = s;  // one-time scattered store
}

// ---------------- per-step SpMM (CSR, scalar edge stream, 8-deep) ----------------

__global__ __launch_bounds__(256) void spmm64(const int* __restrict__ rp, const int2* __restrict__ ev,
                                              const float* __restrict__ Xin, float* __restrict__ Sout) {
    int w = __builtin_amdgcn_readfirstlane((blockIdx.x * blockDim.x + threadIdx.x) >> 6);
    int lane = threadIdx.x & 63;
    if (w >= NN) return;
    int e0 = __builtin_amdgcn_readfirstlane(rp[w]);
    int e1 = __builtin_amdgcn_readfirstlane(rp[w + 1]);
    const float* xl = Xin + lane;
    float a0 = 0.f, a1 = 0.f, a2 = 0.f, a3 = 0.f, a4 = 0.f, a5 = 0.f, a6 = 0.f, a7 = 0.f;
    int e = e0;
    for (; e + 8 <= e1; e += 8) {
        int2 q0 = ev[e + 0], q1 = ev[e + 1], q2 = ev[e + 2], q3 = ev[e + 3];
        int2 q4 = ev[e + 4], q5 = ev[e + 5], q6 = ev[e + 6], q7 = ev[e + 7];
        a0 = fmaf(__int_as_float(q0.y), xl[(size_t)q0.x * 64], a0);
        a1 = fmaf(__int_as_float(q1.y), xl[(size_t)q1.x * 64], a1);
        a2 = fmaf(__int_as_float(q2.y), xl[(size_t)q2.x * 64], a2);
        a3 = fmaf(__int_as_float(q3.y), xl[(size_t)q3.x * 64], a3);
        a4 = fmaf(__int_as_float(q4.y), xl[(size_t)q4.x * 64], a4);
        a5 = fmaf(__int_as_float(q5.y), xl[(size_t)q5.x * 64], a5);
        a6 = fmaf(__int_as_float(q6.y), xl[(size_t)q6.x * 64], a6);
        a7 = fmaf(__int_as_float(q7.y), xl[(size_t)q7.x * 64], a7);
    }
    for (; e < e1; ++e) {
        int2 q = ev[e];
        a0 = fmaf(__int_as_float(q.y), xl[(size_t)q.x * 64], a0);
    }
    Sout[(size_t)w * 64 + lane] = ((a0 + a1) + (a2 + a3)) + ((a4 + a5) + (a6 + a7));
}

// ---------------- cand_update (unchanged body) ----------------

__global__ __launch_bounds__(256) void cand_update(const float* __restrict__ S2, const float* __restrict__ Sx,
                                                   const float* __restrict__ Wc, const float* __restrict__ bc,
                                                   const float* __restrict__ u1, float* __restrict__ h1,
                                                   const float* __restrict__ Wbg, const float* __restrict__ Wbc,
                                                   const float* __restrict__ Wug, const float* __restrict__ Wuc,
                                                   float* __restrict__ z8) {
    int j = threadIdx.x & 63;
    int g = threadIdx.x >> 6;
    float w[65];
#pragma unroll
    for (int k = 0; k < 65; ++k) w[k] = Wc[k * 64 + j];
    float bj = bc[j];
    float wz0 = Wbg[j * 2], wz1 = Wbg[j * 2 + 1], wz2 = Wbc[j];
    float wz3 = Wug[j * 2], wz4 = Wug[j * 2 + 1], wz5 = Wuc[j];
    for (int n = blockIdx.x * 4 + g; n < NN; n += gridDim.x * 4) {
        float acc = fmaf(Sx[n], w[0], bj);
        const float4* s2 = (const float4*)(S2 + (size_t)n * 64);
#pragma unroll
        for (int q = 0; q < 16; ++q) {
            float4 sv = s2[q];
            acc = fmaf(sv.x, w[1 + 4 * q], acc);
            acc = fmaf(sv.y, w[2 + 4 * q], acc);
            acc = fmaf(sv.z, w[3 + 4 * q], acc);
            acc = fmaf(sv.w, w[4 + 4 * q], acc);
        }
        float c = tanh_f(acc);
        float u = u1[(size_t)n * 64 + j];
        float ho = h1[(size_t)n * 64 + j];
        float hn = fmaf(u, ho - c, c);  // u*h + (1-u)*c
        h1[(size_t)n * 64 + j] = hn;
        float p0 = hn * wz0, p1 = hn * wz1, p2 = hn * wz2;
        float p3 = hn * wz3, p4 = hn * wz4, p5 = hn * wz5;
#pragma unroll
        for (int off = 1; off < 64; off <<= 1) {
            p0 += __shfl_xor(p0, off);
            p1 += __shfl_xor(p1, off);
            p2 += __shfl_xor(p2, off);
            p3 += __shfl_xor(p3, off);
            p4 += __shfl_xor(p4, off);
            p5 += __shfl_xor(p5, off);
        }
        if (j == 0) {
            z8[(size_t)n * 8 + 0] = p0; z8[(size_t)n * 8 + 1] = p1; z8[(size_t)n * 8 + 2] = p2;
            z8[(size_t)n * 8 + 3] = p3; z8[(size_t)n * 8 + 4] = p4; z8[(size_t)n * 8 + 5] = p5;
        }
    }
}

// ---------------- merged1: [spmm_h -> Sh(t+1)] || [spmm8_gate2(t)] ----------------
// Blocks [0,GA): gather h1 rows into Sh (identical to spmm64 body).
// Blocks [GA,...): spmm over z8 (8 lanes/row) + gate2 epilogue.

__global__ __launch_bounds__(256) void merged1(int GA,
        const int* __restrict__ rp, const int2* __restrict__ ev,
        const float* __restrict__ h1, float* __restrict__ Sh,
        const float* __restrict__ z8,
        const float* __restrict__ hb, const float* __restrict__ hu,
        const float* __restrict__ Wbg, const float* __restrict__ bbg,
        const float* __restrict__ Wug, const float* __restrict__ bug,
        float* __restrict__ z2, float* __restrict__ g2, float* __restrict__ S3c) {
    if ((int)blockIdx.x < GA) {
        int w = __builtin_amdgcn_readfirstlane(((int)blockIdx.x * 256 + (int)threadIdx.x) >> 6);
        int lane = threadIdx.x & 63;
        if (w >= NN) return;
        int e0 = __builtin_amdgcn_readfirstlane(rp[w]);
        int e1 = __builtin_amdgcn_readfirstlane(rp[w + 1]);
        const float* xl = h1 + lane;
        float a0 = 0.f, a1 = 0.f, a2 = 0.f, a3 = 0.f, a4 = 0.f, a5 = 0.f, a6 = 0.f, a7 = 0.f;
        int e = e0;
        for (; e + 8 <= e1; e += 8) {
            int2 q0 = ev[e + 0], q1 = ev[e + 1], q2 = ev[e + 2], q3 = ev[e + 3];
            int2 q4 = ev[e + 4], q5 = ev[e + 5], q6 = ev[e + 6], q7 = ev[e + 7];
            a0 = fmaf(__int_as_float(q0.y), xl[(size_t)q0.x * 64], a0);
            a1 = fmaf(__int_as_float(q1.y), xl[(size_t)q1.x * 64], a1);
            a2 = fmaf(__int_as_float(q2.y), xl[(size_t)q2.x * 64], a2);
            a3 = fmaf(__int_as_float(q3.y), xl[(size_t)q3.x * 64], a3);
            a4 = fmaf(__int_as_float(q4.y), xl[(size_t)q4.x * 64], a4);
            a5 = fmaf(__int_as_float(q5.y), xl[(size_t)q5.x * 64], a5);
            a6 = fmaf(__int_as_float(q6.y), xl[(size_t)q6.x * 64], a6);
            a7 = fmaf(__int_as_float(q7.y), xl[(size_t)q7.x * 64], a7);
        }
        for (; e < e1; ++e) {
            int2 q = ev[e];
            a0 = fmaf(__int_as_float(q.y), xl[(size_t)q.x * 64], a0);
        }
        Sh[(size_t)w * 64 + lane] = ((a0 + a1) + (a2 + a3)) + ((a4 + a5) + (a6 + a7));
    } else {
        int gid = ((int)blockIdx.x - GA) * 256 + threadIdx.x;
        int row = gid >> 3;
        int j = gid & 7;
        if (row >= NN) return;
        int e = rp[row], e1 = rp[row + 1];
        float a0 = 0.f, a1 = 0.f, a2 = 0.f, a3 = 0.f;
        for (; e + 3 < e1; e += 4) {
            int2 p0 = ev[e], p1 = ev[e + 1], p2 = ev[e + 2], p3 = ev[e + 3];
            a0 = fmaf(__int_as_float(p0.y), z8[(size_t)p0.x * 8 + j], a0);
            a1 = fmaf(__int_as_float(p1.y), z8[(size_t)p1.x * 8 + j], a1);
            a2 = fmaf(__int_as_float(p2.y), z8[(size_t)p2.x * 8 + j], a2);
            a3 = fmaf(__int_as_float(p3.y), z8[(size_t)p3.x * 8 + j], a3);
        }
        for (; e < e1; ++e) {
            int2 p = ev[e];
            a0 = fmaf(__int_as_float(p.y), z8[(size_t)p.x * 8 + j], a0);
        }
        float s = (a0 + a1) + (a2 + a3);
        if (j == 2) S3c[row * 2 + 0] = s;
        if (j == 5) S3c[row * 2 + 1] = s;
        int lane = threadIdx.x & 63;
        int base = lane & ~7;
        float s0 = __shfl(s, base + 0);
        float s1 = __shfl(s, base + 1);
        float s3 = __shfl(s, base + 3);
        float s4 = __shfl(s, base + 4);
        float s6 = __shfl(s, base + 6);
        float s7 = __shfl(s, base + 7);
        if (j == 0) {
            float rb = sigm(fmaf(s6, Wbg[128], s0) + bbg[0]);
            float ub = sigm(fmaf(s6, Wbg[129], s1) + bbg[1]);
            float ru = sigm(fmaf(s7, Wug[128], s3) + bug[0]);
            float uu = sigm(fmaf(s7, Wug[129], s4) + bug[1]);
            z2[row * 2 + 0] = rb * hb[row];
            z2[row * 2 + 1] = ru * hu[row];
            g2[row * 2 + 0] = ub;
            g2[row * 2 + 1] = uu;
        }
    }
}

// ---------------- merged2: [gate1(t)] || [spmm2_update2(t-1)] (blockDim 128) ----------------

#define G1_CHUNK 32
__global__ __launch_bounds__(128) void merged2(int GA,
        const float* __restrict__ Sh, const float* __restrict__ Sx,
        const float* __restrict__ Wg, const float* __restrict__ bg,
        const float* __restrict__ h1, float* __restrict__ rh, float* __restrict__ u1,
        const int* __restrict__ rp, const int2* __restrict__ ev,
        const float* __restrict__ z2, const float* __restrict__ S3c, const float* __restrict__ g2,
        const float* __restrict__ Wbc, const float* __restrict__ bbc,
        const float* __restrict__ Wuc, const float* __restrict__ buc,
        float* __restrict__ hb, float* __restrict__ hu,
        float* __restrict__ z8, float* __restrict__ out, int tPrev) {
    __shared__ float4 s4[G1_CHUNK][16];
    __shared__ float sxl[G1_CHUNK];
    if ((int)blockIdx.x < GA) {
        int j = threadIdx.x;  // 0..127 output column
        float w0 = Wg[j];
        float wk[64];
#pragma unroll
        for (int k = 0; k < 64; ++k) wk[k] = Wg[(1 + k) * 128 + j];
        float bj = bg[j];
        int n0 = (int)blockIdx.x * G1_CHUNK;
        int nmax = min(G1_CHUNK, NN - n0);
        for (int idx = j; idx < G1_CHUNK * 16; idx += 128) {
            int n = idx >> 4, q = idx & 15;
            if (n < nmax) s4[n][q] = *(const float4*)(Sh + (size_t)(n0 + n) * 64 + q * 4);
        }
        if (j < G1_CHUNK && j < nmax) sxl[j] = Sx[n0 + j];
        __syncthreads();
        for (int n = 0; n < nmax; ++n) {
            float acc = fmaf(sxl[n], w0, bj);
#pragma unroll
            for (int q = 0; q < 16; ++q) {
                float4 sv = s4[n][q];  // broadcast read
                acc = fmaf(sv.x, wk[4 * q + 0], acc);
                acc = fmaf(sv.y, wk[4 * q + 1], acc);
                acc = fmaf(sv.z, wk[4 * q + 2], acc);
                acc = fmaf(sv.w, wk[4 * q + 3], acc);
            }
            float g = sigm(acc);
            int node = n0 + n;
            if (j < 64) rh[(size_t)node * 64 + j] = g * h1[(size_t)node * 64 + j];
            else        u1[(size_t)node * 64 + (j - 64)] = g;
        }
    } else {
        int gid = ((int)blockIdx.x - GA) * 128 + threadIdx.x;
        int row = gid >> 1;
        int j = gid & 1;
        if (row >= NN) return;
        int e = rp[row], e1 = rp[row + 1];
        float a0 = 0.f, a1 = 0.f, a2 = 0.f, a3 = 0.f;
        for (; e + 3 < e1; e += 4) {
            int2 p0 = ev[e], p1 = ev[e + 1], p2 = ev[e + 2], p3 = ev[e + 3];
            a0 = fmaf(__int_as_float(p0.y), z2[(size_t)p0.x * 2 + j], a0);
            a1 = fmaf(__int_as_float(p1.y), z2[(size_t)p1.x * 2 + j], a1);
            a2 = fmaf(__int_as_float(p2.y), z2[(size_t)p2.x * 2 + j], a2);
            a3 = fmaf(__int_as_float(p3.y), z2[(size_t)p3.x * 2 + j], a3);
        }
        for (; e < e1; ++e) {
            int2 p = ev[e];
            a0 = fmaf(__int_as_float(p.y), z2[(size_t)p.x * 2 + j], a0);
        }
        float s = (a0 + a1) + (a2 + a3);
        int lane = threadIdx.x & 63;
        int base = lane & ~1;
        float sA = __shfl(s, base + 0);
        float sB = __shfl(s, base + 1);
        if (j == 0) {
            float cb = tanh_f(fmaf(sA, Wbc[64], S3c[row * 2 + 0]) + bbc[0]);
            float cu = tanh_f(fmaf(sB, Wuc[64], S3c[row * 2 + 1]) + buc[0]);
            float ub = g2[row * 2 + 0], uu = g2[row * 2 + 1];
            float hbn = fmaf(ub, hb[row] - cb, cb);
            float hun = fmaf(uu, hu[row] - cu, cu);
            hb[row] = hbn; hu[row] = hun;
            z8[(size_t)row * 8 + 6] = hbn;
            z8[(size_t)row * 8 + 7] = hun;
            out[(size_t)tPrev * NN + row] = hbn;
            out[(size_t)(TT + tPrev) * NN + row] = hun;
        }
    }
}

// ---------------- host ----------------

extern "C" void kernel_launch(void* const* d_in, const int* in_sizes, int n_in,
                              void* d_out, int out_size, void* d_ws, size_t ws_size,
                              hipStream_t stream) {
    const float* features = (const float*)d_in[0];
    const int*   index    = (const int*)d_in[1];
    const float* value    = (const float*)d_in[2];
    const float* W1g  = (const float*)d_in[3];
    const float* b1g  = (const float*)d_in[4];
    const float* W1c  = (const float*)d_in[5];
    const float* b1c  = (const float*)d_in[6];
    const float* W2bg = (const float*)d_in[7];
    const float* b2bg = (const float*)d_in[8];
    const float* W2bc = (const float*)d_in[9];
    const float* b2bc = (const float*)d_in[10];
    const float* W2ug = (const float*)d_in[11];
    const float* b2ug = (const float*)d_in[12];
    const float* W2uc = (const float*)d_in[13];
    const float* b2uc = (const float*)d_in[14];
    float* out = (float*)d_out;

    char* ws = (char*)d_ws;
    size_t o = 0;
    auto alloc = [&](size_t bytes) { size_t cur = o; o += (bytes + 255) & ~(size_t)255; return cur; };
    // zero-init region: h1, hb, hu, z8 (contiguous)
    size_t o_h1  = alloc((size_t)NN * 64 * 4);
    size_t o_hb  = alloc((size_t)NN * 4);
    size_t o_hu  = alloc((size_t)NN * 4);
    size_t o_z8  = alloc((size_t)NN * 8 * 4);
    size_t zeroEnd = o;
    size_t o_rp  = alloc((size_t)(NN + 1) * 4);
    size_t o_cnt = alloc((size_t)NN * 4);
    size_t o_ev  = alloc((size_t)EE * 8);
    size_t o_Sh  = alloc((size_t)NN * 64 * 4);
    size_t o_SxA = alloc((size_t)TT * NN * 4);
    size_t o_rh  = alloc((size_t)NN * 64 * 4);
    size_t o_u1  = alloc((size_t)NN * 64 * 4);
    size_t o_S2  = alloc((size_t)NN * 64 * 4);   // doubles as xT during setup
    size_t o_S3c = alloc((size_t)NN * 2 * 4);
    size_t o_z2  = alloc((size_t)NN * 2 * 4);
    size_t o_g2  = alloc((size_t)NN * 2 * 4);
    (void)ws_size; (void)in_sizes; (void)n_in; (void)out_size;

    float* h1  = (float*)(ws + o_h1);
    float* hb  = (float*)(ws + o_hb);
    float* hu  = (float*)(ws + o_hu);
    float* z8  = (float*)(ws + o_z8);
    int*   rp  = (int*)(ws + o_rp);
    int*   cnt = (int*)(ws + o_cnt);
    int2*  ev  = (int2*)(ws + o_ev);
    float* Sh  = (float*)(ws + o_Sh);
    float* SxA = (float*)(ws + o_SxA);
    float* rh  = (float*)(ws + o_rh);
    float* u1  = (float*)(ws + o_u1);
    float* S2  = (float*)(ws + o_S2);
    float* S3c = (float*)(ws + o_S3c);
    float* z2  = (float*)(ws + o_z2);
    float* g2  = (float*)(ws + o_g2);
    float* xT  = S2;  // alias: only used before first spmm64

    // CSR build
    (void)hipMemsetAsync(ws + o_cnt, 0, (size_t)NN * 4, stream);
    hist_kernel<<<(EE + 255) / 256, 256, 0, stream>>>(index, cnt);
    scan_kernel<<<1, 1024, 0, stream>>>(cnt, rp);
    (void)hipMemsetAsync(ws + o_cnt, 0, (size_t)NN * 4, stream);
    scatter_kernel<<<(EE + 255) / 256, 256, 0, stream>>>(index, value, rp, cnt, ev);

    // zero states + Sh(0) (h1(0)=0 => A@h1=0)
    (void)hipMemsetAsync(ws + o_h1, 0, zeroEnd - o_h1, stream);
    (void)hipMemsetAsync(ws + o_Sh, 0, (size_t)NN * 64 * 4, stream);

    // one-time x precompute: SxA[t][n] = (A @ x_t)[n]
    transpose_x<<<(NN + 63) / 64, 256, 0, stream>>>(features, xT);
    spmm_sx<<<(NN + 3) / 4, 256, 0, stream>>>(rp, ev, xT, SxA);

    const int GA1 = (NN + 3) / 4;            // 12500 blocks (spmm_h)
    const int GB1 = (NN * 8 + 255) / 256;    // 1563 blocks (spmm8_gate2)
    const int GA2 = (NN + G1_CHUNK - 1) / G1_CHUNK;  // 1563 blocks (gate1)
    const int GB2 = (NN * 2 + 127) / 128;    // 782 blocks (spmm2_update2)

    for (int t = 0; t < TT; ++t) {
        const float* Sxt = SxA + (size_t)t * NN;
        // gate1(t)  ||  spmm2_update2(t-1)
        int g2grid = (t > 0) ? (GA2 + GB2) : GA2;
        merged2<<<g2grid, 128, 0, stream>>>(GA2, Sh, Sxt, W1g, b1g, h1, rh, u1,
                                            rp, ev, z2, S3c, g2, W2bc, b2bc, W2uc, b2uc,
                                            hb, hu, z8, out, t - 1);
        spmm64<<<(NN + 3) / 4, 256, 0, stream>>>(rp, ev, rh, S2);
        cand_update<<<1024, 256, 0, stream>>>(S2, Sxt, W1c, b1c, u1, h1, W2bg, W2bc, W2ug, W2uc, z8);
        // spmm_h -> Sh(t+1)  ||  spmm8_gate2(t)
        int gA = (t < TT - 1) ? GA1 : 0;
        merged1<<<gA + GB1, 256, 0, stream>>>(gA, rp, ev, h1, Sh,
                                              z8, hb, hu, W2bg, b2bg, W2ug, b2ug, z2, g2, S3c);
    }
    // final spmm2_update2(t=49)
    merged2<<<GB2, 128, 0, stream>>>(0, Sh, SxA, W1g, b1g, h1, rh, u1,
                                     rp, ev, z2, S3c, g2, W2bc, b2bc, W2uc, b2uc,
                                     hb, hu, z8, out, TT - 1);
}

// Round 9
// 6255.059 us; speedup vs baseline: 1.7910x; 1.2045x over previous
//
#include <hip/hip_runtime.h>
#include <math.h>

#define NN 50000
#define EE 800000
#define TT 50
#define EVCAP 1150016  // 800000 + 7*50000 + slack (padded CSR capacity)
#define SB 196         // (NN + 255) / 256 scan blocks

__device__ __forceinline__ float sigm(float x)   { return 1.f / (1.f + __expf(-x)); }
__device__ __forceinline__ float tanh_f(float x) { float e = __expf(2.f * x); return 1.f - 2.f / (e + 1.f); }

// ---------------- CSR build (counting sort by row, rows padded to %8) ----------------

__global__ __launch_bounds__(256) void hist_kernel(const int* __restrict__ idx, int* __restrict__ cnt) {
    int e = blockIdx.x * blockDim.x + threadIdx.x;
    if (e < EE) atomicAdd(&cnt[idx[2 * e]], 1);
}

// per-block inclusive scan of padded counts; rp[g+1] = block-local inclusive, bsum[b] = block total
__global__ __launch_bounds__(256) void scan1(const int* __restrict__ cnt, int* __restrict__ rp,
                                             int* __restrict__ bsum) {
    __shared__ int s[256];
    int t = threadIdx.x;
    int g = blockIdx.x * 256 + t;
    int v = (g < NN) ? ((cnt[g] + 7) & ~7) : 0;
    s[t] = v;
    __syncthreads();
    for (int off = 1; off < 256; off <<= 1) {
        int add = (t >= off) ? s[t - off] : 0;
        __syncthreads();
        v += add;
        s[t] = v;
        __syncthreads();
    }
    if (g < NN) rp[g + 1] = v;
    if (t == 255) bsum[blockIdx.x] = v;
}

// single-block inclusive scan of the SB block sums (in place)
__global__ __launch_bounds__(256) void scan2(int* __restrict__ bsum) {
    __shared__ int s[256];
    int t = threadIdx.x;
    int v = (t < SB) ? bsum[t] : 0;
    s[t] = v;
    __syncthreads();
    for (int off = 1; off < 256; off <<= 1) {
        int add = (t >= off) ? s[t - off] : 0;
        __syncthreads();
        v += add;
        s[t] = v;
        __syncthreads();
    }
    if (t < SB) bsum[t] = v;
}

__global__ __launch_bounds__(256) void scan3(int* __restrict__ rp, const int* __restrict__ bsum) {
    int g = blockIdx.x * 256 + threadIdx.x;
    int off = (blockIdx.x > 0) ? bsum[blockIdx.x - 1] : 0;
    if (g < NN) rp[g + 1] += off;
    if (g == 0) rp[0] = 0;
}

// edge record: .x = col, .y = bit-cast float value. Pad slots stay (0, 0.0f) from memset.
__global__ __launch_bounds__(256) void scatter_kernel(const int* __restrict__ idx, const float* __restrict__ val,
                                                      const int* __restrict__ rp, int* __restrict__ cnt,
                                                      int2* __restrict__ ev) {
    int e = blockIdx.x * blockDim.x + threadIdx.x;
    if (e >= EE) return;
    int r = idx[2 * e];
    int p = rp[r] + atomicAdd(&cnt[r], 1);
    ev[p] = make_int2(idx[2 * e + 1], __float_as_int(val[e]));
}

// ---------------- one-time x precompute ----------------

// features (T x N) -> xT (N x 64), t in [50,64) zero-padded
__global__ __launch_bounds__(256) void transpose_x(const float* __restrict__ F, float* __restrict__ xT) {
    __shared__ float tile[64][51];
    int n0 = blockIdx.x * 64;
    for (int i = threadIdx.x; i < TT * 64; i += 256) {
        int t = i >> 6, n = i & 63;
        if (n0 + n < NN) tile[n][t] = F[(size_t)t * NN + n0 + n];
    }
    __syncthreads();
    for (int i = threadIdx.x; i < 64 * 64; i += 256) {
        int n = i >> 6, t = i & 63;
        if (n0 + n < NN) xT[(size_t)(n0 + n) * 64 + t] = (t < TT) ? tile[n][t] : 0.f;
    }
}

// SxAll[t][w] = sum_e v_e * xT[col_e][t]  (one pass for all 50 steps; rows padded %8)
__global__ __launch_bounds__(256) void spmm_sx(const int* __restrict__ rp, const int2* __restrict__ ev,
                                               const float* __restrict__ xT, float* __restrict__ SxAll) {
    int w = __builtin_amdgcn_readfirstlane((blockIdx.x * blockDim.x + threadIdx.x) >> 6);
    int lane = threadIdx.x & 63;
    if (w >= NN) return;
    int e  = __builtin_amdgcn_readfirstlane(rp[w]);
    int e1 = __builtin_amdgcn_readfirstlane(rp[w + 1]);
    const float* xl = xT + lane;
    float a0 = 0.f, a1 = 0.f, a2 = 0.f, a3 = 0.f, a4 = 0.f, a5 = 0.f, a6 = 0.f, a7 = 0.f;
    for (; e < e1; e += 8) {
        int2 q0 = ev[e + 0], q1 = ev[e + 1], q2 = ev[e + 2], q3 = ev[e + 3];
        int2 q4 = ev[e + 4], q5 = ev[e + 5], q6 = ev[e + 6], q7 = ev[e + 7];
        a0 = fmaf(__int_as_float(q0.y), xl[(size_t)q0.x * 64], a0);
        a1 = fmaf(__int_as_float(q1.y), xl[(size_t)q1.x * 64], a1);
        a2 = fmaf(__int_as_float(q2.y), xl[(size_t)q2.x * 64], a2);
        a3 = fmaf(__int_as_float(q3.y), xl[(size_t)q3.x * 64], a3);
        a4 = fmaf(__int_as_float(q4.y), xl[(size_t)q4.x * 64], a4);
        a5 = fmaf(__int_as_float(q5.y), xl[(size_t)q5.x * 64], a5);
        a6 = fmaf(__int_as_float(q6.y), xl[(size_t)q6.x * 64], a6);
        a7 = fmaf(__int_as_float(q7.y), xl[(size_t)q7.x * 64], a7);
    }
    float s = ((a0 + a1) + (a2 + a3)) + ((a4 + a5) + (a6 + a7));
    if (lane < TT) SxAll[(size_t)lane * NN + w] = s;  // one-time scattered store
}

// ---------------- fused: S2 = A@rh (gather) + cand GEMM + h1 update + z8[0..5] ----------------
// One wave per row per iteration. S2 row never touches global memory: staged in per-wave
// LDS, consumed by broadcast reads against W1_c held in block LDS.

__global__ __launch_bounds__(256) void spmm_cand(const int* __restrict__ rp, const int2* __restrict__ ev,
        const float* __restrict__ rh, const float* __restrict__ Sx,
        const float* __restrict__ Wc, const float* __restrict__ bc,
        const float* __restrict__ u1, float* __restrict__ h1,
        const float* __restrict__ Wbg, const float* __restrict__ Wbc,
        const float* __restrict__ Wug, const float* __restrict__ Wuc,
        float* __restrict__ z8) {
    __shared__ float ldsW[65 * 64];   // Wc row-major: ldsW[k*64+j]
    __shared__ float ldsS[4][64];     // per-wave S2 row stage
    int t = threadIdx.x;
    for (int i = t; i < 65 * 16; i += 256)
        ((float4*)ldsW)[i] = ((const float4*)Wc)[i];
    __syncthreads();
    int lane = t & 63;
    int wv = t >> 6;
    int j = lane;
    float bj = bc[j];
    float wz0 = Wbg[j * 2], wz1 = Wbg[j * 2 + 1], wz2 = Wbc[j];
    float wz3 = Wug[j * 2], wz4 = Wug[j * 2 + 1], wz5 = Wuc[j];
    int wstride = gridDim.x * 4;
    for (int wi = blockIdx.x * 4 + wv; wi < NN; wi += wstride) {
        int w = __builtin_amdgcn_readfirstlane(wi);
        int e  = __builtin_amdgcn_readfirstlane(rp[w]);
        int e1 = __builtin_amdgcn_readfirstlane(rp[w + 1]);
        const float* xl = rh + lane;
        float a0 = 0.f, a1 = 0.f, a2 = 0.f, a3 = 0.f, a4 = 0.f, a5 = 0.f, a6 = 0.f, a7 = 0.f;
        for (; e < e1; e += 8) {
            int2 q0 = ev[e + 0], q1 = ev[e + 1], q2 = ev[e + 2], q3 = ev[e + 3];
            int2 q4 = ev[e + 4], q5 = ev[e + 5], q6 = ev[e + 6], q7 = ev[e + 7];
            a0 = fmaf(__int_as_float(q0.y), xl[(size_t)q0.x * 64], a0);
            a1 = fmaf(__int_as_float(q1.y), xl[(size_t)q1.x * 64], a1);
            a2 = fmaf(__int_as_float(q2.y), xl[(size_t)q2.x * 64], a2);
            a3 = fmaf(__int_as_float(q3.y), xl[(size_t)q3.x * 64], a3);
            a4 = fmaf(__int_as_float(q4.y), xl[(size_t)q4.x * 64], a4);
            a5 = fmaf(__int_as_float(q5.y), xl[(size_t)q5.x * 64], a5);
            a6 = fmaf(__int_as_float(q6.y), xl[(size_t)q6.x * 64], a6);
            a7 = fmaf(__int_as_float(q7.y), xl[(size_t)q7.x * 64], a7);
        }
        float s2 = ((a0 + a1) + (a2 + a3)) + ((a4 + a5) + (a6 + a7));
        ldsS[wv][lane] = s2;  // same-wave producer/consumer; compiler inserts lgkmcnt
        float acc = fmaf(Sx[w], ldsW[j], bj);
#pragma unroll 8
        for (int k = 0; k < 64; ++k)
            acc = fmaf(ldsS[wv][k], ldsW[(k + 1) * 64 + j], acc);
        float c = tanh_f(acc);
        float u  = u1[(size_t)w * 64 + j];
        float ho = h1[(size_t)w * 64 + j];
        float hn = fmaf(u, ho - c, c);  // u*h + (1-u)*c
        h1[(size_t)w * 64 + j] = hn;
        float p0 = hn * wz0, p1 = hn * wz1, p2 = hn * wz2;
        float p3 = hn * wz3, p4 = hn * wz4, p5 = hn * wz5;
#pragma unroll
        for (int off = 1; off < 64; off <<= 1) {
            p0 += __shfl_xor(p0, off);
            p1 += __shfl_xor(p1, off);
            p2 += __shfl_xor(p2, off);
            p3 += __shfl_xor(p3, off);
            p4 += __shfl_xor(p4, off);
            p5 += __shfl_xor(p5, off);
        }
        if (j == 0) {
            z8[(size_t)w * 8 + 0] = p0; z8[(size_t)w * 8 + 1] = p1; z8[(size_t)w * 8 + 2] = p2;
            z8[(size_t)w * 8 + 3] = p3; z8[(size_t)w * 8 + 4] = p4; z8[(size_t)w * 8 + 5] = p5;
        }
    }
}

// ---------------- merged1: [spmm_h -> Sh(t+1)] || [spmm8_gate2(t)] ----------------

__global__ __launch_bounds__(256) void merged1(int GA,
        const int* __restrict__ rp, const int2* __restrict__ ev,
        const float* __restrict__ h1, float* __restrict__ Sh,
        const float* __restrict__ z8,
        const float* __restrict__ hb, const float* __restrict__ hu,
        const float* __restrict__ Wbg, const float* __restrict__ bbg,
        const float* __restrict__ Wug, const float* __restrict__ bug,
        float* __restrict__ z2, float* __restrict__ g2, float* __restrict__ S3c) {
    if ((int)blockIdx.x < GA) {
        int w = __builtin_amdgcn_readfirstlane(((int)blockIdx.x * 256 + (int)threadIdx.x) >> 6);
        int lane = threadIdx.x & 63;
        if (w >= NN) return;
        int e  = __builtin_amdgcn_readfirstlane(rp[w]);
        int e1 = __builtin_amdgcn_readfirstlane(rp[w + 1]);
        const float* xl = h1 + lane;
        float a0 = 0.f, a1 = 0.f, a2 = 0.f, a3 = 0.f, a4 = 0.f, a5 = 0.f, a6 = 0.f, a7 = 0.f;
        for (; e < e1; e += 8) {
            int2 q0 = ev[e + 0], q1 = ev[e + 1], q2 = ev[e + 2], q3 = ev[e + 3];
            int2 q4 = ev[e + 4], q5 = ev[e + 5], q6 = ev[e + 6], q7 = ev[e + 7];
            a0 = fmaf(__int_as_float(q0.y), xl[(size_t)q0.x * 64], a0);
            a1 = fmaf(__int_as_float(q1.y), xl[(size_t)q1.x * 64], a1);
            a2 = fmaf(__int_as_float(q2.y), xl[(size_t)q2.x * 64], a2);
            a3 = fmaf(__int_as_float(q3.y), xl[(size_t)q3.x * 64], a3);
            a4 = fmaf(__int_as_float(q4.y), xl[(size_t)q4.x * 64], a4);
            a5 = fmaf(__int_as_float(q5.y), xl[(size_t)q5.x * 64], a5);
            a6 = fmaf(__int_as_float(q6.y), xl[(size_t)q6.x * 64], a6);
            a7 = fmaf(__int_as_float(q7.y), xl[(size_t)q7.x * 64], a7);
        }
        Sh[(size_t)w * 64 + lane] = ((a0 + a1) + (a2 + a3)) + ((a4 + a5) + (a6 + a7));
    } else {
        int gid = ((int)blockIdx.x - GA) * 256 + threadIdx.x;
        int row = gid >> 3;
        int j = gid & 7;
        if (row >= NN) return;
        int e = rp[row], e1 = rp[row + 1];
        float a0 = 0.f, a1 = 0.f, a2 = 0.f, a3 = 0.f;
        for (; e + 3 < e1; e += 4) {
            int2 p0 = ev[e], p1 = ev[e + 1], p2 = ev[e + 2], p3 = ev[e + 3];
            a0 = fmaf(__int_as_float(p0.y), z8[(size_t)p0.x * 8 + j], a0);
            a1 = fmaf(__int_as_float(p1.y), z8[(size_t)p1.x * 8 + j], a1);
            a2 = fmaf(__int_as_float(p2.y), z8[(size_t)p2.x * 8 + j], a2);
            a3 = fmaf(__int_as_float(p3.y), z8[(size_t)p3.x * 8 + j], a3);
        }
        for (; e < e1; ++e) {
            int2 p = ev[e];
            a0 = fmaf(__int_as_float(p.y), z8[(size_t)p.x * 8 + j], a0);
        }
        float s = (a0 + a1) + (a2 + a3);
        if (j == 2) S3c[row * 2 + 0] = s;
        if (j == 5) S3c[row * 2 + 1] = s;
        int lane = threadIdx.x & 63;
        int base = lane & ~7;
        float s0 = __shfl(s, base + 0);
        float s1 = __shfl(s, base + 1);
        float s3 = __shfl(s, base + 3);
        float s4 = __shfl(s, base + 4);
        float s6 = __shfl(s, base + 6);
        float s7 = __shfl(s, base + 7);
        if (j == 0) {
            float rb = sigm(fmaf(s6, Wbg[128], s0) + bbg[0]);
            float ub = sigm(fmaf(s6, Wbg[129], s1) + bbg[1]);
            float ru = sigm(fmaf(s7, Wug[128], s3) + bug[0]);
            float uu = sigm(fmaf(s7, Wug[129], s4) + bug[1]);
            z2[row * 2 + 0] = rb * hb[row];
            z2[row * 2 + 1] = ru * hu[row];
            g2[row * 2 + 0] = ub;
            g2[row * 2 + 1] = uu;
        }
    }
}

// ---------------- merged2: [gate1(t)] || [spmm2_update2(t-1)] (blockDim 128) ----------------

#define G1_CHUNK 32
__global__ __launch_bounds__(128) void merged2(int GA,
        const float* __restrict__ Sh, const float* __restrict__ Sx,
        const float* __restrict__ Wg, const float* __restrict__ bg,
        const float* __restrict__ h1, float* __restrict__ rh, float* __restrict__ u1,
        const int* __restrict__ rp, const int2* __restrict__ ev,
        const float* __restrict__ z2, const float* __restrict__ S3c, const float* __restrict__ g2,
        const float* __restrict__ Wbc, const float* __restrict__ bbc,
        const float* __restrict__ Wuc, const float* __restrict__ buc,
        float* __restrict__ hb, float* __restrict__ hu,
        float* __restrict__ z8, float* __restrict__ out, int tPrev) {
    __shared__ float4 s4[G1_CHUNK][16];
    __shared__ float sxl[G1_CHUNK];
    if ((int)blockIdx.x < GA) {
        int j = threadIdx.x;  // 0..127 output column
        float w0 = Wg[j];
        float wk[64];
#pragma unroll
        for (int k = 0; k < 64; ++k) wk[k] = Wg[(1 + k) * 128 + j];
        float bj = bg[j];
        int n0 = (int)blockIdx.x * G1_CHUNK;
        int nmax = min(G1_CHUNK, NN - n0);
        for (int idx = j; idx < G1_CHUNK * 16; idx += 128) {
            int n = idx >> 4, q = idx & 15;
            if (n < nmax) s4[n][q] = *(const float4*)(Sh + (size_t)(n0 + n) * 64 + q * 4);
        }
        if (j < G1_CHUNK && j < nmax) sxl[j] = Sx[n0 + j];
        __syncthreads();
        for (int n = 0; n < nmax; ++n) {
            float acc = fmaf(sxl[n], w0, bj);
#pragma unroll
            for (int q = 0; q < 16; ++q) {
                float4 sv = s4[n][q];  // broadcast read
                acc = fmaf(sv.x, wk[4 * q + 0], acc);
                acc = fmaf(sv.y, wk[4 * q + 1], acc);
                acc = fmaf(sv.z, wk[4 * q + 2], acc);
                acc = fmaf(sv.w, wk[4 * q + 3], acc);
            }
            float g = sigm(acc);
            int node = n0 + n;
            if (j < 64) rh[(size_t)node * 64 + j] = g * h1[(size_t)node * 64 + j];
            else        u1[(size_t)node * 64 + (j - 64)] = g;
        }
    } else {
        int gid = ((int)blockIdx.x - GA) * 128 + threadIdx.x;
        int row = gid >> 1;
        int j = gid & 1;
        if (row >= NN) return;
        int e = rp[row], e1 = rp[row + 1];
        float a0 = 0.f, a1 = 0.f, a2 = 0.f, a3 = 0.f;
        for (; e + 3 < e1; e += 4) {
            int2 p0 = ev[e], p1 = ev[e + 1], p2 = ev[e + 2], p3 = ev[e + 3];
            a0 = fmaf(__int_as_float(p0.y), z2[(size_t)p0.x * 2 + j], a0);
            a1 = fmaf(__int_as_float(p1.y), z2[(size_t)p1.x * 2 + j], a1);
            a2 = fmaf(__int_as_float(p2.y), z2[(size_t)p2.x * 2 + j], a2);
            a3 = fmaf(__int_as_float(p3.y), z2[(size_t)p3.x * 2 + j], a3);
        }
        for (; e < e1; ++e) {
            int2 p = ev[e];
            a0 = fmaf(__int_as_float(p.y), z2[(size_t)p.x * 2 + j], a0);
        }
        float s = (a0 + a1) + (a2 + a3);
        int lane = threadIdx.x & 63;
        int base = lane & ~1;
        float sA = __shfl(s, base + 0);
        float sB = __shfl(s, base + 1);
        if (j == 0) {
            float cb = tanh_f(fmaf(sA, Wbc[64], S3c[row * 2 + 0]) + bbc[0]);
            float cu = tanh_f(fmaf(sB, Wuc[64], S3c[row * 2 + 1]) + buc[0]);
            float ub = g2[row * 2 + 0], uu = g2[row * 2 + 1];
            float hbn = fmaf(ub, hb[row] - cb, cb);
            float hun = fmaf(uu, hu[row] - cu, cu);
            hb[row] = hbn; hu[row] = hun;
            z8[(size_t)row * 8 + 6] = hbn;
            z8[(size_t)row * 8 + 7] = hun;
            out[(size_t)tPrev * NN + row] = hbn;
            out[(size_t)(TT + tPrev) * NN + row] = hun;
        }
    }
}

// ---------------- host ----------------

extern "C" void kernel_launch(void* const* d_in, const int* in_sizes, int n_in,
                              void* d_out, int out_size, void* d_ws, size_t ws_size,
                              hipStream_t stream) {
    const float* features = (const float*)d_in[0];
    const int*   index    = (const int*)d_in[1];
    const float* value    = (const float*)d_in[2];
    const float* W1g  = (const float*)d_in[3];
    const float* b1g  = (const float*)d_in[4];
    const float* W1c  = (const float*)d_in[5];
    const float* b1c  = (const float*)d_in[6];
    const float* W2bg = (const float*)d_in[7];
    const float* b2bg = (const float*)d_in[8];
    const float* W2bc = (const float*)d_in[9];
    const float* b2bc = (const float*)d_in[10];
    const float* W2ug = (const float*)d_in[11];
    const float* b2ug = (const float*)d_in[12];
    const float* W2uc = (const float*)d_in[13];
    const float* b2uc = (const float*)d_in[14];
    float* out = (float*)d_out;

    char* ws = (char*)d_ws;
    size_t o = 0;
    auto alloc = [&](size_t bytes) { size_t cur = o; o += (bytes + 255) & ~(size_t)255; return cur; };
    // zero-init region: h1, hb, hu, z8 (contiguous)
    size_t o_h1  = alloc((size_t)NN * 64 * 4);
    size_t o_hb  = alloc((size_t)NN * 4);
    size_t o_hu  = alloc((size_t)NN * 4);
    size_t o_z8  = alloc((size_t)NN * 8 * 4);
    size_t zeroEnd = o;
    size_t o_rp  = alloc((size_t)(NN + 1) * 4);
    size_t o_cnt = alloc((size_t)NN * 4);
    size_t o_bs  = alloc((size_t)256 * 4);
    size_t o_ev  = alloc((size_t)EVCAP * 8);
    size_t o_Sh  = alloc((size_t)NN * 64 * 4);
    size_t o_SxA = alloc((size_t)TT * NN * 4);
    size_t o_rh  = alloc((size_t)NN * 64 * 4);  // doubles as xT during setup
    size_t o_u1  = alloc((size_t)NN * 64 * 4);
    size_t o_S3c = alloc((size_t)NN * 2 * 4);
    size_t o_z2  = alloc((size_t)NN * 2 * 4);
    size_t o_g2  = alloc((size_t)NN * 2 * 4);
    (void)ws_size; (void)in_sizes; (void)n_in; (void)out_size;

    float* h1  = (float*)(ws + o_h1);
    float* hb  = (float*)(ws + o_hb);
    float* hu  = (float*)(ws + o_hu);
    float* z8  = (float*)(ws + o_z8);
    int*   rp  = (int*)(ws + o_rp);
    int*   cnt = (int*)(ws + o_cnt);
    int*   bsum = (int*)(ws + o_bs);
    int2*  ev  = (int2*)(ws + o_ev);
    float* Sh  = (float*)(ws + o_Sh);
    float* SxA = (float*)(ws + o_SxA);
    float* rh  = (float*)(ws + o_rh);
    float* u1  = (float*)(ws + o_u1);
    float* S3c = (float*)(ws + o_S3c);
    float* z2  = (float*)(ws + o_z2);
    float* g2  = (float*)(ws + o_g2);
    float* xT  = rh;  // alias: only used before gate1(t=0)

    // CSR build (rows padded to multiple of 8; pad slots are (0, 0.0f))
    (void)hipMemsetAsync(ws + o_cnt, 0, (size_t)NN * 4, stream);
    hist_kernel<<<(EE + 255) / 256, 256, 0, stream>>>(index, cnt);
    scan1<<<SB, 256, 0, stream>>>(cnt, rp, bsum);
    scan2<<<1, 256, 0, stream>>>(bsum);
    scan3<<<SB, 256, 0, stream>>>(rp, bsum);
    (void)hipMemsetAsync(ws + o_cnt, 0, (size_t)NN * 4, stream);
    (void)hipMemsetAsync(ws + o_ev, 0, (size_t)EVCAP * 8, stream);
    scatter_kernel<<<(EE + 255) / 256, 256, 0, stream>>>(index, value, rp, cnt, ev);

    // zero states + Sh(0) (h1(0)=0 => A@h1=0)
    (void)hipMemsetAsync(ws + o_h1, 0, zeroEnd - o_h1, stream);
    (void)hipMemsetAsync(ws + o_Sh, 0, (size_t)NN * 64 * 4, stream);

    // one-time x precompute: SxA[t][n] = (A @ x_t)[n]
    transpose_x<<<(NN + 63) / 64, 256, 0, stream>>>(features, xT);
    spmm_sx<<<(NN + 3) / 4, 256, 0, stream>>>(rp, ev, xT, SxA);

    const int GA1 = (NN + 3) / 4;                    // 12500 blocks (spmm_h)
    const int GB1 = (NN * 8 + 255) / 256;            // 1563 blocks (spmm8_gate2)
    const int GA2 = (NN + G1_CHUNK - 1) / G1_CHUNK;  // 1563 blocks (gate1)
    const int GB2 = (NN * 2 + 127) / 128;            // 782 blocks (spmm2_update2)

    for (int t = 0; t < TT; ++t) {
        const float* Sxt = SxA + (size_t)t * NN;
        // gate1(t)  ||  spmm2_update2(t-1)
        int g2grid = (t > 0) ? (GA2 + GB2) : GA2;
        merged2<<<g2grid, 128, 0, stream>>>(GA2, Sh, Sxt, W1g, b1g, h1, rh, u1,
                                            rp, ev, z2, S3c, g2, W2bc, b2bc, W2uc, b2uc,
                                            hb, hu, z8, out, t - 1);
        // S2-gather + candidate + h1 update + z8[0..5], fused
        spmm_cand<<<2048, 256, 0, stream>>>(rp, ev, rh, Sxt, W1c, b1c, u1, h1,
                                            W2bg, W2bc, W2ug, W2uc, z8);
        // spmm_h -> Sh(t+1)  ||  spmm8_gate2(t)
        int gA = (t < TT - 1) ? GA1 : 0;
        merged1<<<gA + GB1, 256, 0, stream>>>(gA, rp, ev, h1, Sh,
                                              z8, hb, hu, W2bg, b2bg, W2ug, b2ug, z2, g2, S3c);
    }
    // final spmm2_update2(t=49)
    merged2<<<GB2, 128, 0, stream>>>(0, Sh, SxA, W1g, b1g, h1, rh, u1,
                                     rp, ev, z2, S3c, g2, W2bc, b2bc, W2uc, b2uc,
                                     hb, hu, z8, out, TT - 1);
}